// Round 7
// baseline (382.677 us; speedup 1.0000x reference)
//
#include <hip/hip_runtime.h>

// ---------------------------------------------------------------------------
// TransformerLayer on MI355X (gfx950), bf16-MFMA pipeline.
// B=2, S=2048, D_MODEL=1024, N_HEADS=16, D_K=64, D_FF=4096, mask=0 (runtime).
// R12: attn LDS-traffic restructure: 512 thr / 8 waves, q-tile 128;
//      wave (g,wlow) = key-half g (32 keys) x 2 m-tiles (32 q) -> per-CU LDS
//      cycles ~0.67x. Cross-wave O/lsum combine once per pass via dead sP.
//      grid (32 bh, 8 pairs), 2 passes, uniform 34 iters. GEMMs/LN unchanged.
// ---------------------------------------------------------------------------

typedef __attribute__((ext_vector_type(8))) __bf16 bf16x8;
typedef __attribute__((ext_vector_type(4))) float f32x4;
typedef __attribute__((ext_vector_type(8))) short s16x8;

struct alignas(8)  S4 { short x, y, z, w; };
struct alignas(16) F4 { float x, y, z, w; };

static __device__ __forceinline__ short f2bf(float f) {
  unsigned u = __float_as_uint(f);
  u += 0x7fff + ((u >> 16) & 1);   // RTNE
  return (short)(u >> 16);
}

// native f32->bf16 (v_cvt, RTNE)
static __device__ __forceinline__ short f2bf_fast(float f) {
  union { __bf16 h; short s; } u;
  u.h = (__bf16)f;
  return u.s;
}

#if __has_builtin(__builtin_amdgcn_exp2f)
#define EXP2F(x) __builtin_amdgcn_exp2f(x)
#else
#define EXP2F(x) exp2f(x)
#endif
// 0.125 (1/sqrt(dk)) * log2(e)
#define SM_SCALE 0.18033688011112042f

static __device__ __forceinline__ void store_out(float* p, float v) { *p = v; }
static __device__ __forceinline__ void store_out(short* p, float v) { *p = f2bf(v); }

// async global->LDS, 16B per lane; LDS dest = wave-uniform base + lane*16
#define GLL16(g, l)                                                         \
  __builtin_amdgcn_global_load_lds(                                         \
      (__attribute__((address_space(1))) void*)(g),                         \
      (__attribute__((address_space(3))) void*)(l), 16, 0, 0)

// ---------------------------------------------------------------------------
// f32 -> bf16 elementwise convert, 3 tensors in one dispatch (grid.y selects).
// ---------------------------------------------------------------------------
__global__ __launch_bounds__(256) void cvt_bf16_kernel(
    const float* __restrict__ i0, const float* __restrict__ i1,
    const float* __restrict__ i2, short* __restrict__ o0,
    short* __restrict__ o1, short* __restrict__ o2) {
  int z = blockIdx.y;
  const float* in = z == 0 ? i0 : (z == 1 ? i1 : i2);
  short* out = z == 0 ? o0 : (z == 1 ? o1 : o2);
  int i = (blockIdx.x * 256 + threadIdx.x) * 4;
  F4 v = *(const F4*)(in + i);
  S4 o = { f2bf(v.x), f2bf(v.y), f2bf(v.z), f2bf(v.w) };
  *(S4*)(out + i) = o;
}

// ---------------------------------------------------------------------------
// All 6 weight transposes (W [K,N] f32 -> Wt [N,K] bf16) in one dispatch.
// ---------------------------------------------------------------------------
__global__ __launch_bounds__(256) void transpose_cvt_kernel(
    const float* __restrict__ Wq, const float* __restrict__ Wk,
    const float* __restrict__ Wv, const float* __restrict__ Wo,
    const float* __restrict__ W1, const float* __restrict__ W2,
    short* __restrict__ Wqt, short* __restrict__ Wkt,
    short* __restrict__ Wvt, short* __restrict__ Wot,
    short* __restrict__ W1t, short* __restrict__ W2t) {
  __shared__ float tile[64][65];
  int bid = blockIdx.x;
  const float* W; short* Wt; int K, N, kx, ny;
  if (bid < 1024) {
    int w = bid >> 8, t = bid & 255;
    W = w == 0 ? Wq : (w == 1 ? Wk : (w == 2 ? Wv : Wo));
    Wt = w == 0 ? Wqt : (w == 1 ? Wkt : (w == 2 ? Wvt : Wot));
    K = 1024; N = 1024; kx = t & 15; ny = t >> 4;
  } else if (bid < 2048) {
    int t = bid - 1024;
    W = W1; Wt = W1t; K = 1024; N = 4096; kx = t & 15; ny = t >> 4;
  } else {
    int t = bid - 2048;
    W = W2; Wt = W2t; K = 4096; N = 1024; kx = t & 63; ny = t >> 6;
  }
  int k0 = kx * 64, n0 = ny * 64;
  int tid = threadIdx.x;
  int rr = tid >> 4, cc = (tid & 15) * 4;
#pragma unroll
  for (int p = 0; p < 4; ++p) {
    int row = p * 16 + rr;
    F4 v = *(const F4*)&W[(long)(k0 + row) * N + n0 + cc];
    tile[row][cc] = v.x; tile[row][cc + 1] = v.y;
    tile[row][cc + 2] = v.z; tile[row][cc + 3] = v.w;
  }
  __syncthreads();
#pragma unroll
  for (int p = 0; p < 4; ++p) {
    int rn = p * 16 + rr;
    S4 o = { f2bf(tile[cc + 0][rn]), f2bf(tile[cc + 1][rn]),
             f2bf(tile[cc + 2][rn]), f2bf(tile[cc + 3][rn]) };
    *(S4*)&Wt[(long)(n0 + rn) * K + k0 + cc] = o;
  }
}

// ---------------------------------------------------------------------------
// gemm256 (used by FFN1/QKV): BM=256, BN=256 (NF=4), BK=64,
// 512 thr / 8 waves as 2m x 4n, 4-phase K-loop, dbuf LDS, counted vmcnt.
// OUT_MODE 0: row-major [M,N].  OUT_MODE 1: [B,H,S,64] head split (N==1024).
// ---------------------------------------------------------------------------
template <int NF, int OUT_MODE, bool RELU, typename OT>
__device__ __forceinline__ void gemm256_core(
    const short* __restrict__ A, const short* __restrict__ Bt,
    const float* __restrict__ bias, OT* __restrict__ out,
    int N, int K, int kBeg, int kEnd, int m0, int n0) {
  constexpr int BN = NF * 64;
  constexpr int LB = BN / 64;        // stage rounds for B
  __shared__ __align__(16) short sA[2][256 * 64];
  __shared__ __align__(16) short sB[2][BN * 64];
  int tid = threadIdx.x;
  int lane = tid & 63, wave = tid >> 6;
  int col = lane & 15, quad = lane >> 4;
  int wm = (wave >> 2) * 128;
  int wn = (wave & 3) * (NF * 16);

  f32x4 acc[8][NF] = {};

  const int NT = (kEnd - kBeg) >> 6;
  const int t0 = kBeg >> 6;

  auto stageA = [&](int buf, int kt) {
#pragma unroll
    for (int j = 0; j < 4; ++j) {
      int idx = j * 512 + tid;
      int row = idx >> 3, cp = idx & 7;
      int c = cp ^ (row & 7);
      GLL16(A + (long)(m0 + row) * K + kt * 64 + c * 8,
            &sA[buf][(j * 512 + (wave << 6)) * 8]);
    }
  };
  auto stageB = [&](int buf, int kt) {
#pragma unroll
    for (int j = 0; j < LB; ++j) {
      int idx = j * 512 + tid;
      int row = idx >> 3, cp = idx & 7;
      int c = cp ^ (row & 7);
      GLL16(Bt + (long)(n0 + row) * K + kt * 64 + c * 8,
            &sB[buf][(j * 512 + (wave << 6)) * 8]);
    }
  };

  stageA(0, t0);     stageB(0, t0);
  stageA(1, t0 + 1); stageB(1, t0 + 1);
  if constexpr (NF == 4) asm volatile("s_waitcnt vmcnt(8)" ::: "memory");
  else                   asm volatile("s_waitcnt vmcnt(6)" ::: "memory");
  __builtin_amdgcn_sched_barrier(0);
  __builtin_amdgcn_s_barrier();

  for (int t = 0; t < NT; ++t) {
    int cur = t & 1;
    bool pf = (t + 2 < NT);
    bf16x8 bf[NF][2], af[2][2];

    // ---- P0: read all B frags + A(mg0); MFMA mg0 ----
#pragma unroll
    for (int n = 0; n < NF; ++n) {
      int rb = wn + n * 16 + col;
#pragma unroll
      for (int kk = 0; kk < 2; ++kk) {
        int ca = kk * 4 + quad;
        bf[n][kk] = *(const bf16x8*)&sB[cur][rb * 64 + ((ca ^ (rb & 7)) << 3)];
      }
    }
#pragma unroll
    for (int i = 0; i < 2; ++i) {
      int ra = wm + i * 16 + col;
#pragma unroll
      for (int kk = 0; kk < 2; ++kk) {
        int ca = kk * 4 + quad;
        af[i][kk] = *(const bf16x8*)&sA[cur][ra * 64 + ((ca ^ (ra & 7)) << 3)];
      }
    }
    asm volatile("s_waitcnt lgkmcnt(0)" ::: "memory");
    __builtin_amdgcn_sched_barrier(0);
    __builtin_amdgcn_s_setprio(1);
#pragma unroll
    for (int i = 0; i < 2; ++i)
#pragma unroll
      for (int n = 0; n < NF; ++n)
#pragma unroll
        for (int kk = 0; kk < 2; ++kk)
          acc[i][n] = __builtin_amdgcn_mfma_f32_16x16x32_bf16(
              af[i][kk], bf[n][kk], acc[i][n], 0, 0, 0);
    __builtin_amdgcn_s_setprio(0);
    __builtin_amdgcn_s_barrier();   // all waves' B reads complete
    __builtin_amdgcn_sched_barrier(0);

    // ---- P1: stage B(t+2); read A(mg1); MFMA mg1 ----
    if (pf) stageB(cur, t0 + t + 2);
#pragma unroll
    for (int i = 0; i < 2; ++i) {
      int ra = wm + (2 + i) * 16 + col;
#pragma unroll
      for (int kk = 0; kk < 2; ++kk) {
        int ca = kk * 4 + quad;
        af[i][kk] = *(const bf16x8*)&sA[cur][ra * 64 + ((ca ^ (ra & 7)) << 3)];
      }
    }
    __builtin_amdgcn_s_setprio(1);
#pragma unroll
    for (int i = 0; i < 2; ++i)
#pragma unroll
      for (int n = 0; n < NF; ++n)
#pragma unroll
        for (int kk = 0; kk < 2; ++kk)
          acc[2 + i][n] = __builtin_amdgcn_mfma_f32_16x16x32_bf16(
              af[i][kk], bf[n][kk], acc[2 + i][n], 0, 0, 0);
    __builtin_amdgcn_s_setprio(0);
    __builtin_amdgcn_s_barrier();

    // ---- P2: read A(mg2); MFMA mg2 ----
#pragma unroll
    for (int i = 0; i < 2; ++i) {
      int ra = wm + (4 + i) * 16 + col;
#pragma unroll
      for (int kk = 0; kk < 2; ++kk) {
        int ca = kk * 4 + quad;
        af[i][kk] = *(const bf16x8*)&sA[cur][ra * 64 + ((ca ^ (ra & 7)) << 3)];
      }
    }
    __builtin_amdgcn_s_setprio(1);
#pragma unroll
    for (int i = 0; i < 2; ++i)
#pragma unroll
      for (int n = 0; n < NF; ++n)
#pragma unroll
        for (int kk = 0; kk < 2; ++kk)
          acc[4 + i][n] = __builtin_amdgcn_mfma_f32_16x16x32_bf16(
              af[i][kk], bf[n][kk], acc[4 + i][n], 0, 0, 0);
    __builtin_amdgcn_s_setprio(0);
    __builtin_amdgcn_s_barrier();

    // ---- P3: read A(mg3); drain; stage A(t+2); MFMA mg3; vmcnt; barrier ----
#pragma unroll
    for (int i = 0; i < 2; ++i) {
      int ra = wm + (6 + i) * 16 + col;
#pragma unroll
      for (int kk = 0; kk < 2; ++kk) {
        int ca = kk * 4 + quad;
        af[i][kk] = *(const bf16x8*)&sA[cur][ra * 64 + ((ca ^ (ra & 7)) << 3)];
      }
    }
    asm volatile("s_waitcnt lgkmcnt(0)" ::: "memory");
    __builtin_amdgcn_sched_barrier(0);
    __builtin_amdgcn_s_barrier();   // all waves' A reads complete
    __builtin_amdgcn_sched_barrier(0);
    if (pf) stageA(cur, t0 + t + 2);
    __builtin_amdgcn_s_setprio(1);
#pragma unroll
    for (int i = 0; i < 2; ++i)
#pragma unroll
      for (int n = 0; n < NF; ++n)
#pragma unroll
        for (int kk = 0; kk < 2; ++kk)
          acc[6 + i][n] = __builtin_amdgcn_mfma_f32_16x16x32_bf16(
              af[i][kk], bf[n][kk], acc[6 + i][n], 0, 0, 0);
    __builtin_amdgcn_s_setprio(0);
    if (pf) {
      if constexpr (NF == 4) asm volatile("s_waitcnt vmcnt(8)" ::: "memory");
      else                   asm volatile("s_waitcnt vmcnt(6)" ::: "memory");
    } else {
      asm volatile("s_waitcnt vmcnt(0)" ::: "memory");
    }
    __builtin_amdgcn_sched_barrier(0);
    __builtin_amdgcn_s_barrier();
  }

  // --- epilogue: C/D layout col=lane&15, row=quad*4+reg ---
#pragma unroll
  for (int m = 0; m < 8; ++m) {
#pragma unroll
    for (int n = 0; n < NF; ++n) {
      int Cc = n0 + wn + n * 16 + col;
      float bv = bias ? bias[Cc] : 0.f;
#pragma unroll
      for (int r = 0; r < 4; ++r) {
        int R = m0 + wm + m * 16 + quad * 4 + r;
        float v = acc[m][n][r] + bv;
        if (RELU) v = v > 0.f ? v : 0.f;
        if (OUT_MODE == 0) {
          store_out(&out[(long)R * N + Cc], v);
        } else {
          int bb = R >> 11, s = R & 2047, h = Cc >> 6, d = Cc & 63;
          store_out(&out[((long)((bb * 16 + h) * 2048 + s) << 6) + d], v);
        }
      }
    }
  }
}

// ---------------------------------------------------------------------------
// gsp128 (used by Wo/FFN2): BM=256, BN=128, BK=64, 512 thr /
// 8 waves as 4m x 2n. Collapsed K-loop, counted vmcnt(6), setprio.
// ---------------------------------------------------------------------------
__device__ __forceinline__ void gsp128_core(
    const short* __restrict__ A, const short* __restrict__ Bt,
    const float* __restrict__ bias, float* __restrict__ out,
    int N, int K, int kBeg, int kEnd, int m0, int n0) {
  __shared__ __align__(16) short sA[2][256 * 64];
  __shared__ __align__(16) short sB[2][128 * 64];
  int tid = threadIdx.x;
  int lane = tid & 63, wave = tid >> 6;
  int col = lane & 15, quad = lane >> 4;
  int wm = (wave >> 1) * 64;   // 4 m-groups of 64 rows
  int wn = (wave & 1) * 64;    // 2 n-groups of 64 cols

  f32x4 acc[4][4] = {};
  const int NT = (kEnd - kBeg) >> 6;
  const int t0 = kBeg >> 6;

  auto stageA = [&](int buf, int kt) {
#pragma unroll
    for (int j = 0; j < 4; ++j) {
      int idx = j * 512 + tid;
      int row = idx >> 3, cp = idx & 7;
      int c = cp ^ (row & 7);
      GLL16(A + (long)(m0 + row) * K + kt * 64 + c * 8,
            &sA[buf][(j * 512 + (wave << 6)) * 8]);
    }
  };
  auto stageB = [&](int buf, int kt) {
#pragma unroll
    for (int j = 0; j < 2; ++j) {
      int idx = j * 512 + tid;
      int row = idx >> 3, cp = idx & 7;
      int c = cp ^ (row & 7);
      GLL16(Bt + (long)(n0 + row) * K + kt * 64 + c * 8,
            &sB[buf][(j * 512 + (wave << 6)) * 8]);
    }
  };

  stageA(0, t0);     stageB(0, t0);
  stageA(1, t0 + 1); stageB(1, t0 + 1);
  asm volatile("s_waitcnt vmcnt(6)" ::: "memory");
  __builtin_amdgcn_s_barrier();

  for (int t = 0; t < NT; ++t) {
    int cur = t & 1;
    bool pf = (t + 2 < NT);
    bf16x8 bf[4][2], af[4][2];

#pragma unroll
    for (int n = 0; n < 4; ++n) {
      int rb = wn + n * 16 + col;
#pragma unroll
      for (int kk = 0; kk < 2; ++kk) {
        int ca = kk * 4 + quad;
        bf[n][kk] = *(const bf16x8*)&sB[cur][rb * 64 + ((ca ^ (rb & 7)) << 3)];
      }
    }
#pragma unroll
    for (int m = 0; m < 4; ++m) {
      int ra = wm + m * 16 + col;
#pragma unroll
      for (int kk = 0; kk < 2; ++kk) {
        int ca = kk * 4 + quad;
        af[m][kk] = *(const bf16x8*)&sA[cur][ra * 64 + ((ca ^ (ra & 7)) << 3)];
      }
    }
    asm volatile("s_waitcnt lgkmcnt(0)" ::: "memory");
    __builtin_amdgcn_s_barrier();        // all waves done reading side cur
    __builtin_amdgcn_sched_barrier(0);   // stages must not hoist above barrier
    if (pf) { stageA(cur, t0 + t + 2); stageB(cur, t0 + t + 2); }
    __builtin_amdgcn_s_setprio(1);
#pragma unroll
    for (int m = 0; m < 4; ++m)
#pragma unroll
      for (int n = 0; n < 4; ++n)
#pragma unroll
        for (int kk = 0; kk < 2; ++kk)
          acc[m][n] = __builtin_amdgcn_mfma_f32_16x16x32_bf16(
              af[m][kk], bf[n][kk], acc[m][n], 0, 0, 0);
    __builtin_amdgcn_s_setprio(0);
    if (pf) asm volatile("s_waitcnt vmcnt(6)" ::: "memory");
    else    asm volatile("s_waitcnt vmcnt(0)" ::: "memory");
    __builtin_amdgcn_s_barrier();        // tile t+1 landed; side swap safe
  }

#pragma unroll
  for (int m = 0; m < 4; ++m) {
#pragma unroll
    for (int n = 0; n < 4; ++n) {
      int Cc = n0 + wn + n * 16 + col;
      float bv = bias ? bias[Cc] : 0.f;
#pragma unroll
      for (int r = 0; r < 4; ++r) {
        int R = m0 + wm + m * 16 + quad * 4 + r;
        out[(long)R * N + Cc] = acc[m][n][r] + bv;
      }
    }
  }
}

// FFN1: [4096,4096,K=1024], relu, bf16 out. grid (16,16).
__global__ __launch_bounds__(512) void g256_ffn1(
    const short* __restrict__ A, const short* __restrict__ Bt,
    const float* __restrict__ bias, short* __restrict__ out) {
  gemm256_core<4, 0, true, short>(A, Bt, bias, out, 4096, 1024, 0, 1024,
                                  blockIdx.x * 256, blockIdx.y * 256);
}

// QKV: grid (16,4,3); z selects (A, Bt, bias, out); head-split output.
__global__ __launch_bounds__(512) void g256_qkv(
    const short* __restrict__ Aq, const short* __restrict__ Ak,
    const short* __restrict__ Av, const short* __restrict__ Btq,
    const short* __restrict__ Btk, const short* __restrict__ Btv,
    const float* __restrict__ bq, const float* __restrict__ bk,
    const float* __restrict__ bv, short* __restrict__ Qp,
    short* __restrict__ Kp, short* __restrict__ Vp) {
  int z = blockIdx.z;
  const short* A = z == 0 ? Aq : (z == 1 ? Ak : Av);
  const short* Bt = z == 0 ? Btq : (z == 1 ? Btk : Btv);
  const float* bias = z == 0 ? bq : (z == 1 ? bk : bv);
  short* out = z == 0 ? Qp : (z == 1 ? Kp : Vp);
  gemm256_core<4, 1, false, short>(A, Bt, bias, out, 1024, 1024, 0, 1024,
                                   blockIdx.x * 256, blockIdx.y * 256);
}

// Wo: [4096,1024,K=1024] split-K=2, BN=128. grid (16,8,2). f32 partials.
__global__ __launch_bounds__(512) void gsp_wo(
    const short* __restrict__ A, const short* __restrict__ Bt,
    const float* __restrict__ bias, float* __restrict__ p0,
    float* __restrict__ p1) {
  int z = blockIdx.z;
  float* out = z == 0 ? p0 : p1;
  const float* b = z == 0 ? bias : nullptr;
  gsp128_core(A, Bt, b, out, 1024, 1024, z * 512, z * 512 + 512,
              blockIdx.x * 256, blockIdx.y * 128);
}

// FFN2: [4096,1024,K=4096] split-K=2, BN=128. grid (16,8,2). f32 partials.
__global__ __launch_bounds__(512) void gsp_ffn2(
    const short* __restrict__ A, const short* __restrict__ Bt,
    const float* __restrict__ bias, float* __restrict__ p0,
    float* __restrict__ p1) {
  int z = blockIdx.z;
  float* out = z == 0 ? p0 : p1;
  const float* b = z == 0 ? bias : nullptr;
  gsp128_core(A, Bt, b, out, 1024, 4096, z * 2048, z * 2048 + 2048,
              blockIdx.x * 256, blockIdx.y * 128);
}

// ---------------------------------------------------------------------------
// Flash attention R12: 512 thr / 8 waves, q-tile 128.
// Wave (g = wave>>2, wlow = wave&3): key-half g (32 keys of each 64-key
// tile) x 2 m-tiles (rows qt*128 + wlow*32 + {0..31}).
// grid (32 bh, 8 pairs); pass 0: qt = pair, pass 1: qt = 15 - pair
// -> every block 34 key-tile iters. 1 block/CU; LDS ~64.5 KB.
// K staged via GLL16 (dbuf), V reg-staged into packed V^T (dbuf).
// Per-pass cross-wave combine: g=1 dumps O partials into dead sP, g=0 adds.
// ---------------------------------------------------------------------------
__global__ __launch_bounds__(512) void attn_kernel(
    const short* __restrict__ Q, const short* __restrict__ K,
    const short* __restrict__ V, const int* __restrict__ maskp,
    short* __restrict__ ctx) {
  __shared__ __align__(16) short sK[2][64 * 64];   // swizzled 8-chunks, 16 KB
  __shared__ __align__(16) int   sVt[2][64 * 32];  // V^T packed pairs, 16 KB
  __shared__ __align__(16) short sP[8 * 32 * 64];  // per-wave P (32q x 64k), 32 KB
  __shared__ float sLred[128];                     // cross-g lsum exchange
  int tid = threadIdx.x, wave = tid >> 6;
  int lane = tid & 63;
  int col = lane & 15, quad = lane >> 4;
  int g = wave >> 2, wlow = wave & 3;
  int bh = blockIdx.x, pair = blockIdx.y;
  int maskv = maskp[0];
  const long base = (long)bh * (2048 * 64);
  int b = bh >> 4, h = bh & 15;

  // staging constants: K 512 chunks of 16B (1/thread); V: 32 key-pairs x
  // 16 d-groups of 4.
  int kp = tid & 31, dg = tid >> 5, d0v = dg * 4;

  for (int pass = 0; pass < 2; ++pass) {
    int qt = pass ? (15 - pair) : pair;
    int iq0 = qt * 128 + wlow * 32;   // wave's first q-row

    long jmax = (long)qt * 128 + 127 + maskv - 1;
    int tot = (jmax < 0) ? 0 : (int)(jmax >> 6) + 1;
    if (tot > 32) tot = 32;

    bf16x8 aQ[2][2];
#pragma unroll
    for (int mt = 0; mt < 2; ++mt)
#pragma unroll
      for (int kk = 0; kk < 2; ++kk)
        aQ[mt][kk] = *(const bf16x8*)&Q[base +
            (long)(iq0 + mt * 16 + col) * 64 + kk * 32 + quad * 8];

    f32x4 o[2][4] = {};
    float lsum[2][4] = {};

    if (tot > 0) {
      // prologue: stage tile 0 into buffer 0
      {
        int row = tid >> 3, cp = tid & 7;
        int c = cp ^ (row & 7);
        GLL16(K + base + (long)row * 64 + c * 8, &sK[0][(wave << 6) * 8]);
      }
      {
        union { S4 v; short s[4]; } u0, u1;
        u0.v = *(const S4*)&V[base + (long)(2 * kp) * 64 + d0v];
        u1.v = *(const S4*)&V[base + (long)(2 * kp + 1) * 64 + d0v];
#pragma unroll
        for (int j = 0; j < 4; ++j) {
          int d = d0v + j;
          int w = ((int)(unsigned short)u1.s[j] << 16) | (unsigned short)u0.s[j];
          sVt[0][d * 32 + ((((kp >> 2) ^ (d & 7)) << 2) | (kp & 3))] = w;
        }
      }
    }
    __syncthreads();

    for (int kt = 0; kt < tot; ++kt) {
      int cur = kt & 1, nxt = cur ^ 1;
      bool pf = (kt + 1 < tot);

      // --- prefetch next tile: K via GLL16, V into registers ---
      union { S4 v; short s[4]; } u0, u1;
      if (pf) {
        int row = tid >> 3, cp = tid & 7;
        int c = cp ^ (row & 7);
        GLL16(K + base + (long)((kt + 1) * 64 + row) * 64 + c * 8,
              &sK[nxt][(wave << 6) * 8]);
        u0.v = *(const S4*)&V[base + (long)((kt + 1) * 64 + 2 * kp) * 64 + d0v];
        u1.v = *(const S4*)&V[base + (long)((kt + 1) * 64 + 2 * kp + 1) * 64 + d0v];
      }

      // --- scores: 2 m-tiles x wave's 32 keys (nt in {2g, 2g+1}) ---
      f32x4 sc[2][2] = {};
      __builtin_amdgcn_s_setprio(1);
#pragma unroll
      for (int kk = 0; kk < 2; ++kk) {
        int ca = kk * 4 + quad;
#pragma unroll
        for (int nt = 0; nt < 2; ++nt) {
          int rk = (2 * g + nt) * 16 + col;
          bf16x8 bK = *(const bf16x8*)&sK[cur][rk * 64 + ((ca ^ (rk & 7)) << 3)];
#pragma unroll
          for (int mt = 0; mt < 2; ++mt)
            sc[mt][nt] = __builtin_amdgcn_mfma_f32_16x16x32_bf16(
                aQ[mt][kk], bK, sc[mt][nt], 0, 0, 0);
        }
      }
      __builtin_amdgcn_s_setprio(0);

      // --- streaming softmax; diagonal-only masking (per wave) ---
      bool interior = (kt * 64 + g * 32 + 31) < (iq0 + maskv);
      if (interior) {
#pragma unroll
        for (int mt = 0; mt < 2; ++mt)
#pragma unroll
          for (int r = 0; r < 4; ++r) {
            int qr = mt * 16 + quad * 4 + r;
#pragma unroll
            for (int nt = 0; nt < 2; ++nt) {
              float p = EXP2F(sc[mt][nt][r] * SM_SCALE);
              lsum[mt][r] += p;
              int k8 = 4 * g + nt * 2 + (col >> 3);
              sP[wave * 2048 + qr * 64 + (((k8 ^ (qr & 7)) << 3) | (col & 7))] =
                  f2bf_fast(p);
            }
          }
      } else {
#pragma unroll
        for (int mt = 0; mt < 2; ++mt)
#pragma unroll
          for (int r = 0; r < 4; ++r) {
            int i = iq0 + mt * 16 + quad * 4 + r;
            int qr = mt * 16 + quad * 4 + r;
#pragma unroll
            for (int nt = 0; nt < 2; ++nt) {
              int j = kt * 64 + (2 * g + nt) * 16 + col;
              float p = (j < i + maskv) ? EXP2F(sc[mt][nt][r] * SM_SCALE) : 0.f;
              lsum[mt][r] += p;
              int k8 = 4 * g + nt * 2 + (col >> 3);
              sP[wave * 2048 + qr * 64 + (((k8 ^ (qr & 7)) << 3) | (col & 7))] =
                  f2bf_fast(p);
            }
          }
      }

      // --- O += P @ V over wave's 32 keys (sP wave-private, no barrier) ---
      {
        int ca = 4 * g + quad;
        bf16x8 bV[4];
#pragma unroll
        for (int dt = 0; dt < 4; ++dt) {
          int d = dt * 16 + col;
          bV[dt] = *(const bf16x8*)((const short*)sVt[cur] + d * 64 +
                                    ((ca ^ (d & 7)) << 3));
        }
        __builtin_amdgcn_s_setprio(1);
#pragma unroll
        for (int mt = 0; mt < 2; ++mt) {
          int rp = mt * 16 + col;
          bf16x8 aP = *(const bf16x8*)&sP[wave * 2048 + rp * 64 +
                                          ((ca ^ (rp & 7)) << 3)];
#pragma unroll
          for (int dt = 0; dt < 4; ++dt)
            o[mt][dt] = __builtin_amdgcn_mfma_f32_16x16x32_bf16(
                aP, bV[dt], o[mt][dt], 0, 0, 0);
        }
        __builtin_amdgcn_s_setprio(0);
      }

      // --- commit prefetched V into sVt[nxt] ---
      if (pf) {
#pragma unroll
        for (int j = 0; j < 4; ++j) {
          int d = d0v + j;
          int w = ((int)(unsigned short)u1.s[j] << 16) | (unsigned short)u0.s[j];
          sVt[nxt][d * 32 + ((((kp >> 2) ^ (d & 7)) << 2) | (kp & 3))] = w;
        }
      }
      __syncthreads();   // drains GLL16 (vmcnt) + V writes before next iter
    }

    // --- epilogue: reduce lsum over the 16 key-lanes (within wave) ---
#pragma unroll
    for (int mt = 0; mt < 2; ++mt)
#pragma unroll
      for (int r = 0; r < 4; ++r)
#pragma unroll
        for (int off = 1; off < 16; off <<= 1)
          lsum[mt][r] += __shfl_xor(lsum[mt][r], off);

    // --- cross-g combine: g=1 dumps O + lsum; g=0 adds and stores ---
    float* od = (float*)sP;           // sP dead until next pass
    int slot = wlow * 64 + lane;      // 32 floats (128B) per slot
    if (g == 1) {
#pragma unroll
      for (int mt = 0; mt < 2; ++mt)
#pragma unroll
        for (int dt = 0; dt < 4; ++dt)
          *(f32x4*)&od[slot * 32 + (((mt * 4 + dt) ^ (lane & 7)) << 2)] =
              o[mt][dt];
      if (col == 0) {
#pragma unroll
        for (int mt = 0; mt < 2; ++mt)
#pragma unroll
          for (int r = 0; r < 4; ++r)
            sLred[wlow * 32 + mt * 16 + quad * 4 + r] = lsum[mt][r];
      }
    }
    __syncthreads();
    if (g == 0) {
#pragma unroll
      for (int mt = 0; mt < 2; ++mt) {
#pragma unroll
        for (int dt = 0; dt < 4; ++dt) {
          f32x4 t = *(const f32x4*)&od[slot * 32 +
                                       (((mt * 4 + dt) ^ (lane & 7)) << 2)];
          o[mt][dt] += t;
        }
      }
#pragma unroll
      for (int mt = 0; mt < 2; ++mt)
#pragma unroll
        for (int r = 0; r < 4; ++r) {
          float ls = lsum[mt][r] + sLred[wlow * 32 + mt * 16 + quad * 4 + r];
          int i = iq0 + mt * 16 + quad * 4 + r;
          float inv = (ls > 0.f) ? 1.f / ls : 0.f;
          if (maskv == 0 && i == 0) inv = 0.f;
#pragma unroll
          for (int dt = 0; dt < 4; ++dt)
            ctx[(long)(b * 2048 + i) * 1024 + h * 64 + dt * 16 + col] =
                f2bf(o[mt][dt][r] * inv);
        }
    }
    __syncthreads();   // O-dump reads done before next pass reuses sP/sK/sVt
  }
}

// ---------------------------------------------------------------------------
// LayerNorm over last dim (1024) of (p0 + p1 + res). One block per row.
// ---------------------------------------------------------------------------
__global__ __launch_bounds__(256) void ln_comb_kernel(
    const float* __restrict__ p0, const float* __restrict__ p1,
    const float* __restrict__ res, const float* __restrict__ g,
    const float* __restrict__ b, float* __restrict__ outf,
    short* __restrict__ outb) {
  int r = blockIdx.x, tid = threadIdx.x;
  int lane = tid & 63, wave = tid >> 6;
  long off0 = (long)r * 1024;
  F4 a = ((const F4*)(p0 + off0))[tid];
  F4 c = ((const F4*)(p1 + off0))[tid];
  F4 d = ((const F4*)(res + off0))[tid];
  F4 v = { a.x + c.x + d.x, a.y + c.y + d.y, a.z + c.z + d.z, a.w + c.w + d.w };
  float s = v.x + v.y + v.z + v.w;
  float sq = v.x * v.x + v.y * v.y + v.z * v.z + v.w * v.w;
#pragma unroll
  for (int off = 1; off < 64; off <<= 1) {
    s += __shfl_xor(s, off);
    sq += __shfl_xor(sq, off);
  }
  __shared__ float rs[4], rq[4];
  if (lane == 0) { rs[wave] = s; rq[wave] = sq; }
  __syncthreads();
  s = rs[0] + rs[1] + rs[2] + rs[3];
  sq = rq[0] + rq[1] + rq[2] + rq[3];
  float mu = s * (1.0f / 1024.0f);
  float var = sq * (1.0f / 1024.0f) - mu * mu;
  float rstd = rsqrtf(var + 1e-5f);
  F4 gv = ((const F4*)g)[tid], bv = ((const F4*)b)[tid];
  F4 o;
  o.x = (v.x - mu) * rstd * gv.x + bv.x;
  o.y = (v.y - mu) * rstd * gv.y + bv.y;
  o.z = (v.z - mu) * rstd * gv.z + bv.z;
  o.w = (v.w - mu) * rstd * gv.w + bv.w;
  ((F4*)(outf + off0))[tid] = o;
  if (outb) {
    S4 ob = { f2bf(o.x), f2bf(o.y), f2bf(o.z), f2bf(o.w) };
    ((S4*)(outb + off0))[tid] = ob;
  }
}

// ---------------------------------------------------------------------------
extern "C" void kernel_launch(void* const* d_in, const int* in_sizes, int n_in,
                              void* d_out, int out_size, void* d_ws, size_t ws_size,
                              hipStream_t stream) {
  const float* query  = (const float*)d_in[0];
  const float* keyi   = (const float*)d_in[1];
  const float* values = (const float*)d_in[2];
  const float* Wq = (const float*)d_in[3];
  const float* bq = (const float*)d_in[4];
  const float* Wk = (const float*)d_in[5];
  const float* bk = (const float*)d_in[6];
  const float* Wv = (const float*)d_in[7];
  const float* bv = (const float*)d_in[8];
  const float* Wo = (const float*)d_in[9];
  const float* bo = (const float*)d_in[10];
  const float* ln1_g = (const float*)d_in[11];
  const float* ln1_b = (const float*)d_in[12];
  const float* W1 = (const float*)d_in[13];
  const float* b1 = (const float*)d_in[14];
  const float* W2 = (const float*)d_in[15];
  const float* b2 = (const float*)d_in[16];
  const float* ln2_g = (const float*)d_in[17];
  const float* ln2_b = (const float*)d_in[18];
  const int*   maskp = (const int*)d_in[19];
  float* out = (float*)d_out;

  char* ws = (char*)d_ws;
  const size_t MB = 1u << 20;
  // Layout (liveness-checked overlays):
  short* q_bf = (short*)(ws + 0);        // 0..8    dead after QKV
  short* k_bf = (short*)(ws + 8 * MB);   // 8..16   dead after QKV
  short* v_bf = (short*)(ws + 16 * MB);  // 16..24  dead after QKV
  short* ctx  = (short*)(ws + 24 * MB);  // 24..32  attn out, dead after Wo
  short* Qp   = (short*)(ws + 32 * MB);  // 32..40  dead after attn
  short* Kp   = (short*)(ws + 40 * MB);  // 40..48  dead after attn
  short* Vp   = (short*)(ws + 48 * MB);  // 48..56  dead after attn
  short* Wqt  = (short*)(ws + 56 * MB);  // 56..58
  short* Wkt  = (short*)(ws + 58 * MB);  // 58..60
  short* Wvt  = (short*)(ws + 60 * MB);  // 60..62
  short* Wot  = (short*)(ws + 62 * MB);  // 62..64
  short* W1t  = (short*)(ws + 64 * MB);  // 64..72
  short* W2t  = (short*)(ws + 72 * MB);  // 72..80
  short* hbuf = (short*)(ws + 80 * MB);  // 80..112 FFN1 out
  // Wo partials: live Wo-gemm -> LN1 (q/k/v_bf, Qp/Kp dead by then)
  float* pWo0 = (float*)(ws + 0);        // 0..16
  float* pWo1 = (float*)(ws + 32 * MB);  // 32..48
  float* x_f32 = (float*)(ws + 16 * MB); // 16..32  LN1 out (v_bf/ctx dead)
  short* x_bf  = (short*)(ws + 48 * MB); // 48..56  LN1 out (Vp dead)
  // FFN2 partials: live FFN2 -> LN2 (pWo dead after LN1)
  float* pF0 = (float*)(ws + 0);         // 0..16
  float* pF1 = (float*)(ws + 32 * MB);   // 32..48

  // 1. activations -> bf16 (one dispatch)
  cvt_bf16_kernel<<<dim3(4096, 3), 256, 0, stream>>>(query, keyi, values,
                                                     q_bf, k_bf, v_bf);
  // 2. all weights -> transposed bf16 [N,K] (one dispatch)
  transpose_cvt_kernel<<<3072, 256, 0, stream>>>(Wq, Wk, Wv, Wo, W1, W2,
                                                 Wqt, Wkt, Wvt, Wot, W1t, W2t);
  // 3. fused QKV projections -> [B,H,S,64] bf16 (192 blocks)
  g256_qkv<<<dim3(16, 4, 3), 512, 0, stream>>>(q_bf, k_bf, v_bf,
                                               Wqt, Wkt, Wvt,
                                               bq, bk, bv, Qp, Kp, Vp);
  // 4. flash attention (q-tile 128, 8 waves, 256 blocks, 34 iters each) -> ctx
  attn_kernel<<<dim3(32, 8), 512, 0, stream>>>(Qp, Kp, Vp, maskp, ctx);
  // 5. output projection, split-K=2, BN=128 (256 blocks) -> partials
  gsp_wo<<<dim3(16, 8, 2), 512, 0, stream>>>(ctx, Wot, bo, pWo0, pWo1);
  // 6. LN1(p0+p1+query) -> x (f32 + bf16)
  ln_comb_kernel<<<4096, 256, 0, stream>>>(pWo0, pWo1, query, ln1_g, ln1_b,
                                           x_f32, x_bf);
  // 7. FFN1 (+relu) -> h bf16 [4096,4096] (256 blocks)
  g256_ffn1<<<dim3(16, 16), 512, 0, stream>>>(x_bf, W1t, b1, hbuf);
  // 8. FFN2, split-K=2, BN=128 (256 blocks) -> partials
  gsp_ffn2<<<dim3(16, 8, 2), 512, 0, stream>>>(hbuf, W2t, b2, pF0, pF1);
  // 9. LN2(p0+p1+x) -> out f32
  ln_comb_kernel<<<4096, 256, 0, stream>>>(pF0, pF1, x_f32, ln2_g, ln2_b,
                                           out, nullptr);

  (void)in_sizes; (void)n_in; (void)out_size; (void)ws_size;
}

// Round 8
// 371.146 us; speedup vs baseline: 1.0311x; 1.0311x over previous
//
#include <hip/hip_runtime.h>

// ---------------------------------------------------------------------------
// TransformerLayer on MI355X (gfx950), bf16-MFMA pipeline.
// B=2, S=2048, D_MODEL=1024, N_HEADS=16, D_K=64, D_FF=4096, mask=0 (runtime).
// R13: attn = R6 key-split geometry in R5's 256-thr shell:
//      4 waves = 2 q-subtiles(32q) x 2 key-halves(32k); q-tile 64;
//      grid (32,16) = 512 blocks, LDS 48.3KB -> 2 blocks/CU co-resident.
//      Cross-g O-combine once per pass, conflict-free f32x4 layout.
//      GEMMs/LN unchanged (R10 cores).
// ---------------------------------------------------------------------------

typedef __attribute__((ext_vector_type(8))) __bf16 bf16x8;
typedef __attribute__((ext_vector_type(4))) float f32x4;
typedef __attribute__((ext_vector_type(8))) short s16x8;

struct alignas(8)  S4 { short x, y, z, w; };
struct alignas(16) F4 { float x, y, z, w; };

static __device__ __forceinline__ short f2bf(float f) {
  unsigned u = __float_as_uint(f);
  u += 0x7fff + ((u >> 16) & 1);   // RTNE
  return (short)(u >> 16);
}

// native f32->bf16 (v_cvt, RTNE)
static __device__ __forceinline__ short f2bf_fast(float f) {
  union { __bf16 h; short s; } u;
  u.h = (__bf16)f;
  return u.s;
}

#if __has_builtin(__builtin_amdgcn_exp2f)
#define EXP2F(x) __builtin_amdgcn_exp2f(x)
#else
#define EXP2F(x) exp2f(x)
#endif
// 0.125 (1/sqrt(dk)) * log2(e)
#define SM_SCALE 0.18033688011112042f

static __device__ __forceinline__ void store_out(float* p, float v) { *p = v; }
static __device__ __forceinline__ void store_out(short* p, float v) { *p = f2bf(v); }

// async global->LDS, 16B per lane; LDS dest = wave-uniform base + lane*16
#define GLL16(g, l)                                                         \
  __builtin_amdgcn_global_load_lds(                                         \
      (__attribute__((address_space(1))) void*)(g),                         \
      (__attribute__((address_space(3))) void*)(l), 16, 0, 0)

// ---------------------------------------------------------------------------
// f32 -> bf16 elementwise convert, 3 tensors in one dispatch (grid.y selects).
// ---------------------------------------------------------------------------
__global__ __launch_bounds__(256) void cvt_bf16_kernel(
    const float* __restrict__ i0, const float* __restrict__ i1,
    const float* __restrict__ i2, short* __restrict__ o0,
    short* __restrict__ o1, short* __restrict__ o2) {
  int z = blockIdx.y;
  const float* in = z == 0 ? i0 : (z == 1 ? i1 : i2);
  short* out = z == 0 ? o0 : (z == 1 ? o1 : o2);
  int i = (blockIdx.x * 256 + threadIdx.x) * 4;
  F4 v = *(const F4*)(in + i);
  S4 o = { f2bf(v.x), f2bf(v.y), f2bf(v.z), f2bf(v.w) };
  *(S4*)(out + i) = o;
}

// ---------------------------------------------------------------------------
// All 6 weight transposes (W [K,N] f32 -> Wt [N,K] bf16) in one dispatch.
// ---------------------------------------------------------------------------
__global__ __launch_bounds__(256) void transpose_cvt_kernel(
    const float* __restrict__ Wq, const float* __restrict__ Wk,
    const float* __restrict__ Wv, const float* __restrict__ Wo,
    const float* __restrict__ W1, const float* __restrict__ W2,
    short* __restrict__ Wqt, short* __restrict__ Wkt,
    short* __restrict__ Wvt, short* __restrict__ Wot,
    short* __restrict__ W1t, short* __restrict__ W2t) {
  __shared__ float tile[64][65];
  int bid = blockIdx.x;
  const float* W; short* Wt; int K, N, kx, ny;
  if (bid < 1024) {
    int w = bid >> 8, t = bid & 255;
    W = w == 0 ? Wq : (w == 1 ? Wk : (w == 2 ? Wv : Wo));
    Wt = w == 0 ? Wqt : (w == 1 ? Wkt : (w == 2 ? Wvt : Wot));
    K = 1024; N = 1024; kx = t & 15; ny = t >> 4;
  } else if (bid < 2048) {
    int t = bid - 1024;
    W = W1; Wt = W1t; K = 1024; N = 4096; kx = t & 15; ny = t >> 4;
  } else {
    int t = bid - 2048;
    W = W2; Wt = W2t; K = 4096; N = 1024; kx = t & 63; ny = t >> 6;
  }
  int k0 = kx * 64, n0 = ny * 64;
  int tid = threadIdx.x;
  int rr = tid >> 4, cc = (tid & 15) * 4;
#pragma unroll
  for (int p = 0; p < 4; ++p) {
    int row = p * 16 + rr;
    F4 v = *(const F4*)&W[(long)(k0 + row) * N + n0 + cc];
    tile[row][cc] = v.x; tile[row][cc + 1] = v.y;
    tile[row][cc + 2] = v.z; tile[row][cc + 3] = v.w;
  }
  __syncthreads();
#pragma unroll
  for (int p = 0; p < 4; ++p) {
    int rn = p * 16 + rr;
    S4 o = { f2bf(tile[cc + 0][rn]), f2bf(tile[cc + 1][rn]),
             f2bf(tile[cc + 2][rn]), f2bf(tile[cc + 3][rn]) };
    *(S4*)&Wt[(long)(n0 + rn) * K + k0 + cc] = o;
  }
}

// ---------------------------------------------------------------------------
// gemm256 (used by FFN1/QKV): BM=256, BN=256 (NF=4), BK=64,
// 512 thr / 8 waves as 2m x 4n, 4-phase K-loop, dbuf LDS, counted vmcnt.
// OUT_MODE 0: row-major [M,N].  OUT_MODE 1: [B,H,S,64] head split (N==1024).
// ---------------------------------------------------------------------------
template <int NF, int OUT_MODE, bool RELU, typename OT>
__device__ __forceinline__ void gemm256_core(
    const short* __restrict__ A, const short* __restrict__ Bt,
    const float* __restrict__ bias, OT* __restrict__ out,
    int N, int K, int kBeg, int kEnd, int m0, int n0) {
  constexpr int BN = NF * 64;
  constexpr int LB = BN / 64;        // stage rounds for B
  __shared__ __align__(16) short sA[2][256 * 64];
  __shared__ __align__(16) short sB[2][BN * 64];
  int tid = threadIdx.x;
  int lane = tid & 63, wave = tid >> 6;
  int col = lane & 15, quad = lane >> 4;
  int wm = (wave >> 2) * 128;
  int wn = (wave & 3) * (NF * 16);

  f32x4 acc[8][NF] = {};

  const int NT = (kEnd - kBeg) >> 6;
  const int t0 = kBeg >> 6;

  auto stageA = [&](int buf, int kt) {
#pragma unroll
    for (int j = 0; j < 4; ++j) {
      int idx = j * 512 + tid;
      int row = idx >> 3, cp = idx & 7;
      int c = cp ^ (row & 7);
      GLL16(A + (long)(m0 + row) * K + kt * 64 + c * 8,
            &sA[buf][(j * 512 + (wave << 6)) * 8]);
    }
  };
  auto stageB = [&](int buf, int kt) {
#pragma unroll
    for (int j = 0; j < LB; ++j) {
      int idx = j * 512 + tid;
      int row = idx >> 3, cp = idx & 7;
      int c = cp ^ (row & 7);
      GLL16(Bt + (long)(n0 + row) * K + kt * 64 + c * 8,
            &sB[buf][(j * 512 + (wave << 6)) * 8]);
    }
  };

  stageA(0, t0);     stageB(0, t0);
  stageA(1, t0 + 1); stageB(1, t0 + 1);
  if constexpr (NF == 4) asm volatile("s_waitcnt vmcnt(8)" ::: "memory");
  else                   asm volatile("s_waitcnt vmcnt(6)" ::: "memory");
  __builtin_amdgcn_sched_barrier(0);
  __builtin_amdgcn_s_barrier();

  for (int t = 0; t < NT; ++t) {
    int cur = t & 1;
    bool pf = (t + 2 < NT);
    bf16x8 bf[NF][2], af[2][2];

    // ---- P0: read all B frags + A(mg0); MFMA mg0 ----
#pragma unroll
    for (int n = 0; n < NF; ++n) {
      int rb = wn + n * 16 + col;
#pragma unroll
      for (int kk = 0; kk < 2; ++kk) {
        int ca = kk * 4 + quad;
        bf[n][kk] = *(const bf16x8*)&sB[cur][rb * 64 + ((ca ^ (rb & 7)) << 3)];
      }
    }
#pragma unroll
    for (int i = 0; i < 2; ++i) {
      int ra = wm + i * 16 + col;
#pragma unroll
      for (int kk = 0; kk < 2; ++kk) {
        int ca = kk * 4 + quad;
        af[i][kk] = *(const bf16x8*)&sA[cur][ra * 64 + ((ca ^ (ra & 7)) << 3)];
      }
    }
    asm volatile("s_waitcnt lgkmcnt(0)" ::: "memory");
    __builtin_amdgcn_sched_barrier(0);
    __builtin_amdgcn_s_setprio(1);
#pragma unroll
    for (int i = 0; i < 2; ++i)
#pragma unroll
      for (int n = 0; n < NF; ++n)
#pragma unroll
        for (int kk = 0; kk < 2; ++kk)
          acc[i][n] = __builtin_amdgcn_mfma_f32_16x16x32_bf16(
              af[i][kk], bf[n][kk], acc[i][n], 0, 0, 0);
    __builtin_amdgcn_s_setprio(0);
    __builtin_amdgcn_s_barrier();   // all waves' B reads complete
    __builtin_amdgcn_sched_barrier(0);

    // ---- P1: stage B(t+2); read A(mg1); MFMA mg1 ----
    if (pf) stageB(cur, t0 + t + 2);
#pragma unroll
    for (int i = 0; i < 2; ++i) {
      int ra = wm + (2 + i) * 16 + col;
#pragma unroll
      for (int kk = 0; kk < 2; ++kk) {
        int ca = kk * 4 + quad;
        af[i][kk] = *(const bf16x8*)&sA[cur][ra * 64 + ((ca ^ (ra & 7)) << 3)];
      }
    }
    __builtin_amdgcn_s_setprio(1);
#pragma unroll
    for (int i = 0; i < 2; ++i)
#pragma unroll
      for (int n = 0; n < NF; ++n)
#pragma unroll
        for (int kk = 0; kk < 2; ++kk)
          acc[2 + i][n] = __builtin_amdgcn_mfma_f32_16x16x32_bf16(
              af[i][kk], bf[n][kk], acc[2 + i][n], 0, 0, 0);
    __builtin_amdgcn_s_setprio(0);
    __builtin_amdgcn_s_barrier();

    // ---- P2: read A(mg2); MFMA mg2 ----
#pragma unroll
    for (int i = 0; i < 2; ++i) {
      int ra = wm + (4 + i) * 16 + col;
#pragma unroll
      for (int kk = 0; kk < 2; ++kk) {
        int ca = kk * 4 + quad;
        af[i][kk] = *(const bf16x8*)&sA[cur][ra * 64 + ((ca ^ (ra & 7)) << 3)];
      }
    }
    __builtin_amdgcn_s_setprio(1);
#pragma unroll
    for (int i = 0; i < 2; ++i)
#pragma unroll
      for (int n = 0; n < NF; ++n)
#pragma unroll
        for (int kk = 0; kk < 2; ++kk)
          acc[4 + i][n] = __builtin_amdgcn_mfma_f32_16x16x32_bf16(
              af[i][kk], bf[n][kk], acc[4 + i][n], 0, 0, 0);
    __builtin_amdgcn_s_setprio(0);
    __builtin_amdgcn_s_barrier();

    // ---- P3: read A(mg3); drain; stage A(t+2); MFMA mg3; vmcnt; barrier ----
#pragma unroll
    for (int i = 0; i < 2; ++i) {
      int ra = wm + (6 + i) * 16 + col;
#pragma unroll
      for (int kk = 0; kk < 2; ++kk) {
        int ca = kk * 4 + quad;
        af[i][kk] = *(const bf16x8*)&sA[cur][ra * 64 + ((ca ^ (ra & 7)) << 3)];
      }
    }
    asm volatile("s_waitcnt lgkmcnt(0)" ::: "memory");
    __builtin_amdgcn_sched_barrier(0);
    __builtin_amdgcn_s_barrier();   // all waves' A reads complete
    __builtin_amdgcn_sched_barrier(0);
    if (pf) stageA(cur, t0 + t + 2);
    __builtin_amdgcn_s_setprio(1);
#pragma unroll
    for (int i = 0; i < 2; ++i)
#pragma unroll
      for (int n = 0; n < NF; ++n)
#pragma unroll
        for (int kk = 0; kk < 2; ++kk)
          acc[6 + i][n] = __builtin_amdgcn_mfma_f32_16x16x32_bf16(
              af[i][kk], bf[n][kk], acc[6 + i][n], 0, 0, 0);
    __builtin_amdgcn_s_setprio(0);
    if (pf) {
      if constexpr (NF == 4) asm volatile("s_waitcnt vmcnt(8)" ::: "memory");
      else                   asm volatile("s_waitcnt vmcnt(6)" ::: "memory");
    } else {
      asm volatile("s_waitcnt vmcnt(0)" ::: "memory");
    }
    __builtin_amdgcn_sched_barrier(0);
    __builtin_amdgcn_s_barrier();
  }

  // --- epilogue: C/D layout col=lane&15, row=quad*4+reg ---
#pragma unroll
  for (int m = 0; m < 8; ++m) {
#pragma unroll
    for (int n = 0; n < NF; ++n) {
      int Cc = n0 + wn + n * 16 + col;
      float bv = bias ? bias[Cc] : 0.f;
#pragma unroll
      for (int r = 0; r < 4; ++r) {
        int R = m0 + wm + m * 16 + quad * 4 + r;
        float v = acc[m][n][r] + bv;
        if (RELU) v = v > 0.f ? v : 0.f;
        if (OUT_MODE == 0) {
          store_out(&out[(long)R * N + Cc], v);
        } else {
          int bb = R >> 11, s = R & 2047, h = Cc >> 6, d = Cc & 63;
          store_out(&out[((long)((bb * 16 + h) * 2048 + s) << 6) + d], v);
        }
      }
    }
  }
}

// ---------------------------------------------------------------------------
// gsp128 (used by Wo/FFN2): BM=256, BN=128, BK=64, 512 thr /
// 8 waves as 4m x 2n. Collapsed K-loop, counted vmcnt(6), setprio.
// ---------------------------------------------------------------------------
__device__ __forceinline__ void gsp128_core(
    const short* __restrict__ A, const short* __restrict__ Bt,
    const float* __restrict__ bias, float* __restrict__ out,
    int N, int K, int kBeg, int kEnd, int m0, int n0) {
  __shared__ __align__(16) short sA[2][256 * 64];
  __shared__ __align__(16) short sB[2][128 * 64];
  int tid = threadIdx.x;
  int lane = tid & 63, wave = tid >> 6;
  int col = lane & 15, quad = lane >> 4;
  int wm = (wave >> 1) * 64;   // 4 m-groups of 64 rows
  int wn = (wave & 1) * 64;    // 2 n-groups of 64 cols

  f32x4 acc[4][4] = {};
  const int NT = (kEnd - kBeg) >> 6;
  const int t0 = kBeg >> 6;

  auto stageA = [&](int buf, int kt) {
#pragma unroll
    for (int j = 0; j < 4; ++j) {
      int idx = j * 512 + tid;
      int row = idx >> 3, cp = idx & 7;
      int c = cp ^ (row & 7);
      GLL16(A + (long)(m0 + row) * K + kt * 64 + c * 8,
            &sA[buf][(j * 512 + (wave << 6)) * 8]);
    }
  };
  auto stageB = [&](int buf, int kt) {
#pragma unroll
    for (int j = 0; j < 2; ++j) {
      int idx = j * 512 + tid;
      int row = idx >> 3, cp = idx & 7;
      int c = cp ^ (row & 7);
      GLL16(Bt + (long)(n0 + row) * K + kt * 64 + c * 8,
            &sB[buf][(j * 512 + (wave << 6)) * 8]);
    }
  };

  stageA(0, t0);     stageB(0, t0);
  stageA(1, t0 + 1); stageB(1, t0 + 1);
  asm volatile("s_waitcnt vmcnt(6)" ::: "memory");
  __builtin_amdgcn_s_barrier();

  for (int t = 0; t < NT; ++t) {
    int cur = t & 1;
    bool pf = (t + 2 < NT);
    bf16x8 bf[4][2], af[4][2];

#pragma unroll
    for (int n = 0; n < 4; ++n) {
      int rb = wn + n * 16 + col;
#pragma unroll
      for (int kk = 0; kk < 2; ++kk) {
        int ca = kk * 4 + quad;
        bf[n][kk] = *(const bf16x8*)&sB[cur][rb * 64 + ((ca ^ (rb & 7)) << 3)];
      }
    }
#pragma unroll
    for (int m = 0; m < 4; ++m) {
      int ra = wm + m * 16 + col;
#pragma unroll
      for (int kk = 0; kk < 2; ++kk) {
        int ca = kk * 4 + quad;
        af[m][kk] = *(const bf16x8*)&sA[cur][ra * 64 + ((ca ^ (ra & 7)) << 3)];
      }
    }
    asm volatile("s_waitcnt lgkmcnt(0)" ::: "memory");
    __builtin_amdgcn_s_barrier();        // all waves done reading side cur
    __builtin_amdgcn_sched_barrier(0);   // stages must not hoist above barrier
    if (pf) { stageA(cur, t0 + t + 2); stageB(cur, t0 + t + 2); }
    __builtin_amdgcn_s_setprio(1);
#pragma unroll
    for (int m = 0; m < 4; ++m)
#pragma unroll
      for (int n = 0; n < 4; ++n)
#pragma unroll
        for (int kk = 0; kk < 2; ++kk)
          acc[m][n] = __builtin_amdgcn_mfma_f32_16x16x32_bf16(
              af[m][kk], bf[n][kk], acc[m][n], 0, 0, 0);
    __builtin_amdgcn_s_setprio(0);
    if (pf) asm volatile("s_waitcnt vmcnt(6)" ::: "memory");
    else    asm volatile("s_waitcnt vmcnt(0)" ::: "memory");
    __builtin_amdgcn_s_barrier();        // tile t+1 landed; side swap safe
  }

#pragma unroll
  for (int m = 0; m < 4; ++m) {
#pragma unroll
    for (int n = 0; n < 4; ++n) {
      int Cc = n0 + wn + n * 16 + col;
      float bv = bias ? bias[Cc] : 0.f;
#pragma unroll
      for (int r = 0; r < 4; ++r) {
        int R = m0 + wm + m * 16 + quad * 4 + r;
        out[(long)R * N + Cc] = acc[m][n][r] + bv;
      }
    }
  }
}

// FFN1: [4096,4096,K=1024], relu, bf16 out. grid (16,16).
__global__ __launch_bounds__(512) void g256_ffn1(
    const short* __restrict__ A, const short* __restrict__ Bt,
    const float* __restrict__ bias, short* __restrict__ out) {
  gemm256_core<4, 0, true, short>(A, Bt, bias, out, 4096, 1024, 0, 1024,
                                  blockIdx.x * 256, blockIdx.y * 256);
}

// QKV: grid (16,4,3); z selects (A, Bt, bias, out); head-split output.
__global__ __launch_bounds__(512) void g256_qkv(
    const short* __restrict__ Aq, const short* __restrict__ Ak,
    const short* __restrict__ Av, const short* __restrict__ Btq,
    const short* __restrict__ Btk, const short* __restrict__ Btv,
    const float* __restrict__ bq, const float* __restrict__ bk,
    const float* __restrict__ bv, short* __restrict__ Qp,
    short* __restrict__ Kp, short* __restrict__ Vp) {
  int z = blockIdx.z;
  const short* A = z == 0 ? Aq : (z == 1 ? Ak : Av);
  const short* Bt = z == 0 ? Btq : (z == 1 ? Btk : Btv);
  const float* bias = z == 0 ? bq : (z == 1 ? bk : bv);
  short* out = z == 0 ? Qp : (z == 1 ? Kp : Vp);
  gemm256_core<4, 1, false, short>(A, Bt, bias, out, 1024, 1024, 0, 1024,
                                   blockIdx.x * 256, blockIdx.y * 256);
}

// Wo: [4096,1024,K=1024] split-K=2, BN=128. grid (16,8,2). f32 partials.
__global__ __launch_bounds__(512) void gsp_wo(
    const short* __restrict__ A, const short* __restrict__ Bt,
    const float* __restrict__ bias, float* __restrict__ p0,
    float* __restrict__ p1) {
  int z = blockIdx.z;
  float* out = z == 0 ? p0 : p1;
  const float* b = z == 0 ? bias : nullptr;
  gsp128_core(A, Bt, b, out, 1024, 1024, z * 512, z * 512 + 512,
              blockIdx.x * 256, blockIdx.y * 128);
}

// FFN2: [4096,1024,K=4096] split-K=2, BN=128. grid (16,8,2). f32 partials.
__global__ __launch_bounds__(512) void gsp_ffn2(
    const short* __restrict__ A, const short* __restrict__ Bt,
    const float* __restrict__ bias, float* __restrict__ p0,
    float* __restrict__ p1) {
  int z = blockIdx.z;
  float* out = z == 0 ? p0 : p1;
  const float* b = z == 0 ? bias : nullptr;
  gsp128_core(A, Bt, b, out, 1024, 4096, z * 2048, z * 2048 + 2048,
              blockIdx.x * 256, blockIdx.y * 128);
}

// ---------------------------------------------------------------------------
// Flash attention R13: 256 thr / 4 waves, q-tile 64.
// Wave (wlow = wave>>1, g = wave&1): q-subtile wlow (32 rows) x key-half g
// (32 of 64 keys). Per-wave work 32q x 32k (same MFMA count as R11's
// 16q x 64k but HALF the bK/bV ds_reads per output area).
// grid (32 bh, 16 pairs); pass 0: qt = pair, pass 1: qt = 31 - pair
// -> every block 33 key-tile iters. LDS 48.3KB -> 512 blocks co-resident
// at 2/CU (3/CU capacity).
// K staged via GLL16 (dbuf), V reg-staged into packed V^T (dbuf).
// Cross-g combine once per pass: g=1 dumps O into dead sP (f32x4-contiguous,
// conflict-free), g=0 adds + normalizes + stores.
// ---------------------------------------------------------------------------
__global__ __launch_bounds__(256) void attn_kernel(
    const short* __restrict__ Q, const short* __restrict__ K,
    const short* __restrict__ V, const int* __restrict__ maskp,
    short* __restrict__ ctx) {
  __shared__ __align__(16) short sK[2][64 * 64];   // swizzled 8-chunks, 16 KB
  __shared__ __align__(16) int   sVt[2][64 * 32];  // V^T packed pairs, 16 KB
  __shared__ __align__(16) short sP[4 * 32 * 64];  // per-wave P (32q x half-k), 16 KB
  __shared__ float sLred[64];                      // cross-g lsum exchange
  int tid = threadIdx.x, wave = tid >> 6;
  int lane = tid & 63;
  int col = lane & 15, quad = lane >> 4;
  int wlow = wave >> 1, g = wave & 1;
  int bh = blockIdx.x, pair = blockIdx.y;
  int maskv = maskp[0];
  const long base = (long)bh * (2048 * 64);
  int b = bh >> 4, h = bh & 15;

  // staging constants: K 512 chunks of 16B (2/thread);
  // V: 32 key-pairs x 8 d-groups of 8.
  int kp = tid & 31, dg = tid >> 5, d0v = dg * 8;

  for (int pass = 0; pass < 2; ++pass) {
    int qt = pass ? (31 - pair) : pair;
    int iq0 = qt * 64 + wlow * 32;    // wave's first q-row

    long jmax = (long)qt * 64 + 63 + maskv - 1;
    int tot = (jmax < 0) ? 0 : (int)(jmax >> 6) + 1;
    if (tot > 32) tot = 32;

    bf16x8 aQ[2][2];
#pragma unroll
    for (int mt = 0; mt < 2; ++mt)
#pragma unroll
      for (int kk = 0; kk < 2; ++kk)
        aQ[mt][kk] = *(const bf16x8*)&Q[base +
            (long)(iq0 + mt * 16 + col) * 64 + kk * 32 + quad * 8];

    f32x4 o[2][4] = {};
    float lsum[2][4] = {};

    if (tot > 0) {
      // prologue: stage tile 0 into buffer 0
#pragma unroll
      for (int j = 0; j < 2; ++j) {
        int idx = j * 256 + tid;
        int row = idx >> 3, cp = idx & 7;
        int c = cp ^ (row & 7);
        GLL16(K + base + (long)row * 64 + c * 8,
              &sK[0][(j * 256 + (wave << 6)) * 8]);
      }
      {
        s16x8 u0 = *(const s16x8*)&V[base + (long)(2 * kp) * 64 + d0v];
        s16x8 u1 = *(const s16x8*)&V[base + (long)(2 * kp + 1) * 64 + d0v];
#pragma unroll
        for (int j = 0; j < 8; ++j) {
          int d = d0v + j;
          int w = ((int)(unsigned short)u1[j] << 16) | (unsigned short)u0[j];
          sVt[0][d * 32 + ((((kp >> 2) ^ (d & 7)) << 2) | (kp & 3))] = w;
        }
      }
    }
    __syncthreads();

    for (int kt = 0; kt < tot; ++kt) {
      int cur = kt & 1, nxt = cur ^ 1;
      bool pf = (kt + 1 < tot);

      // --- prefetch next tile: K via GLL16, V into registers ---
      s16x8 u0, u1;
      if (pf) {
#pragma unroll
        for (int j = 0; j < 2; ++j) {
          int idx = j * 256 + tid;
          int row = idx >> 3, cp = idx & 7;
          int c = cp ^ (row & 7);
          GLL16(K + base + (long)((kt + 1) * 64 + row) * 64 + c * 8,
                &sK[nxt][(j * 256 + (wave << 6)) * 8]);
        }
        u0 = *(const s16x8*)&V[base + (long)((kt + 1) * 64 + 2 * kp) * 64 + d0v];
        u1 = *(const s16x8*)&V[base + (long)((kt + 1) * 64 + 2 * kp + 1) * 64 + d0v];
      }

      // --- scores: 2 m-tiles x wave's 32 keys (nt local, key = 2g+nt) ---
      f32x4 sc[2][2] = {};
      __builtin_amdgcn_s_setprio(1);
#pragma unroll
      for (int kk = 0; kk < 2; ++kk) {
        int ca = kk * 4 + quad;
#pragma unroll
        for (int nt = 0; nt < 2; ++nt) {
          int rk = (2 * g + nt) * 16 + col;
          bf16x8 bK = *(const bf16x8*)&sK[cur][rk * 64 + ((ca ^ (rk & 7)) << 3)];
#pragma unroll
          for (int mt = 0; mt < 2; ++mt)
            sc[mt][nt] = __builtin_amdgcn_mfma_f32_16x16x32_bf16(
                aQ[mt][kk], bK, sc[mt][nt], 0, 0, 0);
        }
      }
      __builtin_amdgcn_s_setprio(0);

      // --- streaming softmax; diagonal-only masking (per wave) ---
      bool interior = (kt * 64 + g * 32 + 31) < (iq0 + maskv);
      if (interior) {
#pragma unroll
        for (int mt = 0; mt < 2; ++mt)
#pragma unroll
          for (int r = 0; r < 4; ++r) {
            int qr = mt * 16 + quad * 4 + r;
#pragma unroll
            for (int nt = 0; nt < 2; ++nt) {
              float p = EXP2F(sc[mt][nt][r] * SM_SCALE);
              lsum[mt][r] += p;
              int k8 = 4 * g + nt * 2 + (col >> 3);
              sP[wave * 2048 + qr * 64 + (((k8 ^ (qr & 7)) << 3) | (col & 7))] =
                  f2bf_fast(p);
            }
          }
      } else {
#pragma unroll
        for (int mt = 0; mt < 2; ++mt)
#pragma unroll
          for (int r = 0; r < 4; ++r) {
            int i = iq0 + mt * 16 + quad * 4 + r;
            int qr = mt * 16 + quad * 4 + r;
#pragma unroll
            for (int nt = 0; nt < 2; ++nt) {
              int j = kt * 64 + (2 * g + nt) * 16 + col;
              float p = (j < i + maskv) ? EXP2F(sc[mt][nt][r] * SM_SCALE) : 0.f;
              lsum[mt][r] += p;
              int k8 = 4 * g + nt * 2 + (col >> 3);
              sP[wave * 2048 + qr * 64 + (((k8 ^ (qr & 7)) << 3) | (col & 7))] =
                  f2bf_fast(p);
            }
          }
      }

      // --- O += P @ V over wave's 32 keys (sP wave-private, no barrier) ---
      {
        int ca = 4 * g + quad;
        bf16x8 bV[4];
#pragma unroll
        for (int dt = 0; dt < 4; ++dt) {
          int d = dt * 16 + col;
          bV[dt] = *(const bf16x8*)((const short*)sVt[cur] + d * 64 +
                                    ((ca ^ (d & 7)) << 3));
        }
        __builtin_amdgcn_s_setprio(1);
#pragma unroll
        for (int mt = 0; mt < 2; ++mt) {
          int rp = mt * 16 + col;
          bf16x8 aP = *(const bf16x8*)&sP[wave * 2048 + rp * 64 +
                                          ((ca ^ (rp & 7)) << 3)];
#pragma unroll
          for (int dt = 0; dt < 4; ++dt)
            o[mt][dt] = __builtin_amdgcn_mfma_f32_16x16x32_bf16(
                aP, bV[dt], o[mt][dt], 0, 0, 0);
        }
        __builtin_amdgcn_s_setprio(0);
      }

      // --- commit prefetched V into sVt[nxt] ---
      if (pf) {
#pragma unroll
        for (int j = 0; j < 8; ++j) {
          int d = d0v + j;
          int w = ((int)(unsigned short)u1[j] << 16) | (unsigned short)u0[j];
          sVt[nxt][d * 32 + ((((kp >> 2) ^ (d & 7)) << 2) | (kp & 3))] = w;
        }
      }
      __syncthreads();   // drains GLL16 (vmcnt) + V writes before next iter
    }

    // --- epilogue: reduce lsum over the 16 key-lanes (within wave) ---
#pragma unroll
    for (int mt = 0; mt < 2; ++mt)
#pragma unroll
      for (int r = 0; r < 4; ++r)
#pragma unroll
        for (int off = 1; off < 16; off <<= 1)
          lsum[mt][r] += __shfl_xor(lsum[mt][r], off);

    // --- cross-g combine: g=1 dumps O + lsum; g=0 adds and stores.
    //     odv layout: [idx(mt*4+dt)][slot(wlow*64+lane)] f32x4 ->
    //     consecutive lanes hit consecutive 16B -> conflict-free.
    f32x4* odv = (f32x4*)sP;          // sP dead until next pass (16 KB = 8*128)
    int slot = wlow * 64 + lane;
    if (g == 1) {
#pragma unroll
      for (int mt = 0; mt < 2; ++mt)
#pragma unroll
        for (int dt = 0; dt < 4; ++dt)
          odv[(mt * 4 + dt) * 128 + slot] = o[mt][dt];
      if (col == 0) {
#pragma unroll
        for (int mt = 0; mt < 2; ++mt)
#pragma unroll
          for (int r = 0; r < 4; ++r)
            sLred[wlow * 32 + mt * 16 + quad * 4 + r] = lsum[mt][r];
      }
    }
    __syncthreads();
    if (g == 0) {
#pragma unroll
      for (int mt = 0; mt < 2; ++mt)
#pragma unroll
        for (int dt = 0; dt < 4; ++dt)
          o[mt][dt] += odv[(mt * 4 + dt) * 128 + slot];
#pragma unroll
      for (int mt = 0; mt < 2; ++mt)
#pragma unroll
        for (int r = 0; r < 4; ++r) {
          float ls = lsum[mt][r] + sLred[wlow * 32 + mt * 16 + quad * 4 + r];
          int i = iq0 + mt * 16 + quad * 4 + r;
          float inv = (ls > 0.f) ? 1.f / ls : 0.f;
          if (maskv == 0 && i == 0) inv = 0.f;
#pragma unroll
          for (int dt = 0; dt < 4; ++dt)
            ctx[(long)(b * 2048 + i) * 1024 + h * 64 + dt * 16 + col] =
                f2bf(o[mt][dt][r] * inv);
        }
    }
    __syncthreads();   // O-dump reads done before next pass reuses sP/sK/sVt
  }
}

// ---------------------------------------------------------------------------
// LayerNorm over last dim (1024) of (p0 + p1 + res). One block per row.
// ---------------------------------------------------------------------------
__global__ __launch_bounds__(256) void ln_comb_kernel(
    const float* __restrict__ p0, const float* __restrict__ p1,
    const float* __restrict__ res, const float* __restrict__ g,
    const float* __restrict__ b, float* __restrict__ outf,
    short* __restrict__ outb) {
  int r = blockIdx.x, tid = threadIdx.x;
  int lane = tid & 63, wave = tid >> 6;
  long off0 = (long)r * 1024;
  F4 a = ((const F4*)(p0 + off0))[tid];
  F4 c = ((const F4*)(p1 + off0))[tid];
  F4 d = ((const F4*)(res + off0))[tid];
  F4 v = { a.x + c.x + d.x, a.y + c.y + d.y, a.z + c.z + d.z, a.w + c.w + d.w };
  float s = v.x + v.y + v.z + v.w;
  float sq = v.x * v.x + v.y * v.y + v.z * v.z + v.w * v.w;
#pragma unroll
  for (int off = 1; off < 64; off <<= 1) {
    s += __shfl_xor(s, off);
    sq += __shfl_xor(sq, off);
  }
  __shared__ float rs[4], rq[4];
  if (lane == 0) { rs[wave] = s; rq[wave] = sq; }
  __syncthreads();
  s = rs[0] + rs[1] + rs[2] + rs[3];
  sq = rq[0] + rq[1] + rq[2] + rq[3];
  float mu = s * (1.0f / 1024.0f);
  float var = sq * (1.0f / 1024.0f) - mu * mu;
  float rstd = rsqrtf(var + 1e-5f);
  F4 gv = ((const F4*)g)[tid], bv = ((const F4*)b)[tid];
  F4 o;
  o.x = (v.x - mu) * rstd * gv.x + bv.x;
  o.y = (v.y - mu) * rstd * gv.y + bv.y;
  o.z = (v.z - mu) * rstd * gv.z + bv.z;
  o.w = (v.w - mu) * rstd * gv.w + bv.w;
  ((F4*)(outf + off0))[tid] = o;
  if (outb) {
    S4 ob = { f2bf(o.x), f2bf(o.y), f2bf(o.z), f2bf(o.w) };
    ((S4*)(outb + off0))[tid] = ob;
  }
}

// ---------------------------------------------------------------------------
extern "C" void kernel_launch(void* const* d_in, const int* in_sizes, int n_in,
                              void* d_out, int out_size, void* d_ws, size_t ws_size,
                              hipStream_t stream) {
  const float* query  = (const float*)d_in[0];
  const float* keyi   = (const float*)d_in[1];
  const float* values = (const float*)d_in[2];
  const float* Wq = (const float*)d_in[3];
  const float* bq = (const float*)d_in[4];
  const float* Wk = (const float*)d_in[5];
  const float* bk = (const float*)d_in[6];
  const float* Wv = (const float*)d_in[7];
  const float* bv = (const float*)d_in[8];
  const float* Wo = (const float*)d_in[9];
  const float* bo = (const float*)d_in[10];
  const float* ln1_g = (const float*)d_in[11];
  const float* ln1_b = (const float*)d_in[12];
  const float* W1 = (const float*)d_in[13];
  const float* b1 = (const float*)d_in[14];
  const float* W2 = (const float*)d_in[15];
  const float* b2 = (const float*)d_in[16];
  const float* ln2_g = (const float*)d_in[17];
  const float* ln2_b = (const float*)d_in[18];
  const int*   maskp = (const int*)d_in[19];
  float* out = (float*)d_out;

  char* ws = (char*)d_ws;
  const size_t MB = 1u << 20;
  // Layout (liveness-checked overlays):
  short* q_bf = (short*)(ws + 0);        // 0..8    dead after QKV
  short* k_bf = (short*)(ws + 8 * MB);   // 8..16   dead after QKV
  short* v_bf = (short*)(ws + 16 * MB);  // 16..24  dead after QKV
  short* ctx  = (short*)(ws + 24 * MB);  // 24..32  attn out, dead after Wo
  short* Qp   = (short*)(ws + 32 * MB);  // 32..40  dead after attn
  short* Kp   = (short*)(ws + 40 * MB);  // 40..48  dead after attn
  short* Vp   = (short*)(ws + 48 * MB);  // 48..56  dead after attn
  short* Wqt  = (short*)(ws + 56 * MB);  // 56..58
  short* Wkt  = (short*)(ws + 58 * MB);  // 58..60
  short* Wvt  = (short*)(ws + 60 * MB);  // 60..62
  short* Wot  = (short*)(ws + 62 * MB);  // 62..64
  short* W1t  = (short*)(ws + 64 * MB);  // 64..72
  short* W2t  = (short*)(ws + 72 * MB);  // 72..80
  short* hbuf = (short*)(ws + 80 * MB);  // 80..112 FFN1 out
  // Wo partials: live Wo-gemm -> LN1 (q/k/v_bf, Qp/Kp dead by then)
  float* pWo0 = (float*)(ws + 0);        // 0..16
  float* pWo1 = (float*)(ws + 32 * MB);  // 32..48
  float* x_f32 = (float*)(ws + 16 * MB); // 16..32  LN1 out (v_bf/ctx dead)
  short* x_bf  = (short*)(ws + 48 * MB); // 48..56  LN1 out (Vp dead)
  // FFN2 partials: live FFN2 -> LN2 (pWo dead after LN1)
  float* pF0 = (float*)(ws + 0);         // 0..16
  float* pF1 = (float*)(ws + 32 * MB);   // 32..48

  // 1. activations -> bf16 (one dispatch)
  cvt_bf16_kernel<<<dim3(4096, 3), 256, 0, stream>>>(query, keyi, values,
                                                     q_bf, k_bf, v_bf);
  // 2. all weights -> transposed bf16 [N,K] (one dispatch)
  transpose_cvt_kernel<<<3072, 256, 0, stream>>>(Wq, Wk, Wv, Wo, W1, W2,
                                                 Wqt, Wkt, Wvt, Wot, W1t, W2t);
  // 3. fused QKV projections -> [B,H,S,64] bf16 (192 blocks)
  g256_qkv<<<dim3(16, 4, 3), 512, 0, stream>>>(q_bf, k_bf, v_bf,
                                               Wqt, Wkt, Wvt,
                                               bq, bk, bv, Qp, Kp, Vp);
  // 4. flash attention (key-split, 512 blocks co-resident 2/CU) -> ctx
  attn_kernel<<<dim3(32, 16), 256, 0, stream>>>(Qp, Kp, Vp, maskp, ctx);
  // 5. output projection, split-K=2, BN=128 (256 blocks) -> partials
  gsp_wo<<<dim3(16, 8, 2), 512, 0, stream>>>(ctx, Wot, bo, pWo0, pWo1);
  // 6. LN1(p0+p1+query) -> x (f32 + bf16)
  ln_comb_kernel<<<4096, 256, 0, stream>>>(pWo0, pWo1, query, ln1_g, ln1_b,
                                           x_f32, x_bf);
  // 7. FFN1 (+relu) -> h bf16 [4096,4096] (256 blocks)
  g256_ffn1<<<dim3(16, 16), 512, 0, stream>>>(x_bf, W1t, b1, hbuf);
  // 8. FFN2, split-K=2, BN=128 (256 blocks) -> partials
  gsp_ffn2<<<dim3(16, 8, 2), 512, 0, stream>>>(hbuf, W2t, b2, pF0, pF1);
  // 9. LN2(p0+p1+x) -> out f32
  ln_comb_kernel<<<4096, 256, 0, stream>>>(pF0, pF1, x_f32, ln2_g, ln2_b,
                                           out, nullptr);

  (void)in_sizes; (void)n_in; (void)out_size; (void)ws_size;
}

// Round 9
// 370.414 us; speedup vs baseline: 1.0331x; 1.0020x over previous
//
#include <hip/hip_runtime.h>

// ---------------------------------------------------------------------------
// TransformerLayer on MI355X (gfx950), bf16-MFMA pipeline.
// B=2, S=2048, D_MODEL=1024, N_HEADS=16, D_K=64, D_FF=4096, mask=0 (runtime).
// R14: FFN1/QKV -> collapsed 2-barrier core (g256c, NF=4), same discipline as
//      the proven gsp128: read-all frags -> lgkm(0) -> barrier -> stage t+2
//      -> setprio MFMA -> counted vmcnt(8) -> barrier. Attn/Wo/FFN2/LN
//      unchanged from R13.
// ---------------------------------------------------------------------------

typedef __attribute__((ext_vector_type(8))) __bf16 bf16x8;
typedef __attribute__((ext_vector_type(4))) float f32x4;
typedef __attribute__((ext_vector_type(8))) short s16x8;

struct alignas(8)  S4 { short x, y, z, w; };
struct alignas(16) F4 { float x, y, z, w; };

static __device__ __forceinline__ short f2bf(float f) {
  unsigned u = __float_as_uint(f);
  u += 0x7fff + ((u >> 16) & 1);   // RTNE
  return (short)(u >> 16);
}

// native f32->bf16 (v_cvt, RTNE)
static __device__ __forceinline__ short f2bf_fast(float f) {
  union { __bf16 h; short s; } u;
  u.h = (__bf16)f;
  return u.s;
}

#if __has_builtin(__builtin_amdgcn_exp2f)
#define EXP2F(x) __builtin_amdgcn_exp2f(x)
#else
#define EXP2F(x) exp2f(x)
#endif
// 0.125 (1/sqrt(dk)) * log2(e)
#define SM_SCALE 0.18033688011112042f

static __device__ __forceinline__ void store_out(float* p, float v) { *p = v; }
static __device__ __forceinline__ void store_out(short* p, float v) { *p = f2bf(v); }

// async global->LDS, 16B per lane; LDS dest = wave-uniform base + lane*16
#define GLL16(g, l)                                                         \
  __builtin_amdgcn_global_load_lds(                                         \
      (__attribute__((address_space(1))) void*)(g),                         \
      (__attribute__((address_space(3))) void*)(l), 16, 0, 0)

// ---------------------------------------------------------------------------
// f32 -> bf16 elementwise convert, 3 tensors in one dispatch (grid.y selects).
// ---------------------------------------------------------------------------
__global__ __launch_bounds__(256) void cvt_bf16_kernel(
    const float* __restrict__ i0, const float* __restrict__ i1,
    const float* __restrict__ i2, short* __restrict__ o0,
    short* __restrict__ o1, short* __restrict__ o2) {
  int z = blockIdx.y;
  const float* in = z == 0 ? i0 : (z == 1 ? i1 : i2);
  short* out = z == 0 ? o0 : (z == 1 ? o1 : o2);
  int i = (blockIdx.x * 256 + threadIdx.x) * 4;
  F4 v = *(const F4*)(in + i);
  S4 o = { f2bf(v.x), f2bf(v.y), f2bf(v.z), f2bf(v.w) };
  *(S4*)(out + i) = o;
}

// ---------------------------------------------------------------------------
// All 6 weight transposes (W [K,N] f32 -> Wt [N,K] bf16) in one dispatch.
// ---------------------------------------------------------------------------
__global__ __launch_bounds__(256) void transpose_cvt_kernel(
    const float* __restrict__ Wq, const float* __restrict__ Wk,
    const float* __restrict__ Wv, const float* __restrict__ Wo,
    const float* __restrict__ W1, const float* __restrict__ W2,
    short* __restrict__ Wqt, short* __restrict__ Wkt,
    short* __restrict__ Wvt, short* __restrict__ Wot,
    short* __restrict__ W1t, short* __restrict__ W2t) {
  __shared__ float tile[64][65];
  int bid = blockIdx.x;
  const float* W; short* Wt; int K, N, kx, ny;
  if (bid < 1024) {
    int w = bid >> 8, t = bid & 255;
    W = w == 0 ? Wq : (w == 1 ? Wk : (w == 2 ? Wv : Wo));
    Wt = w == 0 ? Wqt : (w == 1 ? Wkt : (w == 2 ? Wvt : Wot));
    K = 1024; N = 1024; kx = t & 15; ny = t >> 4;
  } else if (bid < 2048) {
    int t = bid - 1024;
    W = W1; Wt = W1t; K = 1024; N = 4096; kx = t & 15; ny = t >> 4;
  } else {
    int t = bid - 2048;
    W = W2; Wt = W2t; K = 4096; N = 1024; kx = t & 63; ny = t >> 6;
  }
  int k0 = kx * 64, n0 = ny * 64;
  int tid = threadIdx.x;
  int rr = tid >> 4, cc = (tid & 15) * 4;
#pragma unroll
  for (int p = 0; p < 4; ++p) {
    int row = p * 16 + rr;
    F4 v = *(const F4*)&W[(long)(k0 + row) * N + n0 + cc];
    tile[row][cc] = v.x; tile[row][cc + 1] = v.y;
    tile[row][cc + 2] = v.z; tile[row][cc + 3] = v.w;
  }
  __syncthreads();
#pragma unroll
  for (int p = 0; p < 4; ++p) {
    int rn = p * 16 + rr;
    S4 o = { f2bf(tile[cc + 0][rn]), f2bf(tile[cc + 1][rn]),
             f2bf(tile[cc + 2][rn]), f2bf(tile[cc + 3][rn]) };
    *(S4*)&Wt[(long)(n0 + rn) * K + k0 + cc] = o;
  }
}

// ---------------------------------------------------------------------------
// g256c (R14 core, used by FFN1/QKV): BM=256, BN=256, BK=64, 512 thr /
// 8 waves as 2m x 4n (128x64 per wave). Collapsed K-loop (gsp128 discipline):
// {read 24 frags; lgkm(0); barrier; stage t+2 (8 GLL16); setprio + 64 MFMA;
// vmcnt(8) counted; barrier} = 2 barriers/tile.
// OUT_MODE 0: row-major [M,N].  OUT_MODE 1: [B,H,S,64] head split (N==1024).
// ---------------------------------------------------------------------------
template <int OUT_MODE, bool RELU, typename OT>
__device__ __forceinline__ void gemm256c_core(
    const short* __restrict__ A, const short* __restrict__ Bt,
    const float* __restrict__ bias, OT* __restrict__ out,
    int N, int K, int kBeg, int kEnd, int m0, int n0) {
  __shared__ __align__(16) short sA[2][256 * 64];
  __shared__ __align__(16) short sB[2][256 * 64];
  int tid = threadIdx.x;
  int lane = tid & 63, wave = tid >> 6;
  int col = lane & 15, quad = lane >> 4;
  int wm = (wave >> 2) * 128;
  int wn = (wave & 3) * 64;

  f32x4 acc[8][4] = {};
  const int NT = (kEnd - kBeg) >> 6;
  const int t0 = kBeg >> 6;

  auto stageA = [&](int buf, int kt) {
#pragma unroll
    for (int j = 0; j < 4; ++j) {
      int idx = j * 512 + tid;
      int row = idx >> 3, cp = idx & 7;
      int c = cp ^ (row & 7);
      GLL16(A + (long)(m0 + row) * K + kt * 64 + c * 8,
            &sA[buf][(j * 512 + (wave << 6)) * 8]);
    }
  };
  auto stageB = [&](int buf, int kt) {
#pragma unroll
    for (int j = 0; j < 4; ++j) {
      int idx = j * 512 + tid;
      int row = idx >> 3, cp = idx & 7;
      int c = cp ^ (row & 7);
      GLL16(Bt + (long)(n0 + row) * K + kt * 64 + c * 8,
            &sB[buf][(j * 512 + (wave << 6)) * 8]);
    }
  };

  // prologue: stage tiles 0,1; wait tile 0 (leave tile 1's 8 in flight)
  stageA(0, t0);     stageB(0, t0);
  stageA(1, t0 + 1); stageB(1, t0 + 1);
  asm volatile("s_waitcnt vmcnt(8)" ::: "memory");
  __builtin_amdgcn_s_barrier();

  for (int t = 0; t < NT; ++t) {
    int cur = t & 1;
    bool pf = (t + 2 < NT);
    bf16x8 bf[4][2], af[8][2];

    // read all fragments of tile t
#pragma unroll
    for (int n = 0; n < 4; ++n) {
      int rb = wn + n * 16 + col;
#pragma unroll
      for (int kk = 0; kk < 2; ++kk) {
        int ca = kk * 4 + quad;
        bf[n][kk] = *(const bf16x8*)&sB[cur][rb * 64 + ((ca ^ (rb & 7)) << 3)];
      }
    }
#pragma unroll
    for (int m = 0; m < 8; ++m) {
      int ra = wm + m * 16 + col;
#pragma unroll
      for (int kk = 0; kk < 2; ++kk) {
        int ca = kk * 4 + quad;
        af[m][kk] = *(const bf16x8*)&sA[cur][ra * 64 + ((ca ^ (ra & 7)) << 3)];
      }
    }
    asm volatile("s_waitcnt lgkmcnt(0)" ::: "memory");
    __builtin_amdgcn_s_barrier();        // all waves done reading side cur
    __builtin_amdgcn_sched_barrier(0);   // stages must not hoist above barrier
    if (pf) { stageA(cur, t0 + t + 2); stageB(cur, t0 + t + 2); }
    __builtin_amdgcn_s_setprio(1);
#pragma unroll
    for (int m = 0; m < 8; ++m)
#pragma unroll
      for (int n = 0; n < 4; ++n)
#pragma unroll
        for (int kk = 0; kk < 2; ++kk)
          acc[m][n] = __builtin_amdgcn_mfma_f32_16x16x32_bf16(
              af[m][kk], bf[n][kk], acc[m][n], 0, 0, 0);
    __builtin_amdgcn_s_setprio(0);
    if (pf) asm volatile("s_waitcnt vmcnt(8)" ::: "memory");
    else    asm volatile("s_waitcnt vmcnt(0)" ::: "memory");
    __builtin_amdgcn_s_barrier();        // tile t+1 landed; side swap safe
  }

  // epilogue: C/D layout col=lane&15, row=quad*4+reg
#pragma unroll
  for (int m = 0; m < 8; ++m) {
#pragma unroll
    for (int n = 0; n < 4; ++n) {
      int Cc = n0 + wn + n * 16 + col;
      float bv = bias ? bias[Cc] : 0.f;
#pragma unroll
      for (int r = 0; r < 4; ++r) {
        int R = m0 + wm + m * 16 + quad * 4 + r;
        float v = acc[m][n][r] + bv;
        if (RELU) v = v > 0.f ? v : 0.f;
        if (OUT_MODE == 0) {
          store_out(&out[(long)R * N + Cc], v);
        } else {
          int bb = R >> 11, s = R & 2047, h = Cc >> 6, d = Cc & 63;
          store_out(&out[((long)((bb * 16 + h) * 2048 + s) << 6) + d], v);
        }
      }
    }
  }
}

// ---------------------------------------------------------------------------
// gsp128 (used by Wo/FFN2): BM=256, BN=128, BK=64, 512 thr /
// 8 waves as 4m x 2n. Collapsed K-loop, counted vmcnt(6), setprio.
// ---------------------------------------------------------------------------
__device__ __forceinline__ void gsp128_core(
    const short* __restrict__ A, const short* __restrict__ Bt,
    const float* __restrict__ bias, float* __restrict__ out,
    int N, int K, int kBeg, int kEnd, int m0, int n0) {
  __shared__ __align__(16) short sA[2][256 * 64];
  __shared__ __align__(16) short sB[2][128 * 64];
  int tid = threadIdx.x;
  int lane = tid & 63, wave = tid >> 6;
  int col = lane & 15, quad = lane >> 4;
  int wm = (wave >> 1) * 64;   // 4 m-groups of 64 rows
  int wn = (wave & 1) * 64;    // 2 n-groups of 64 cols

  f32x4 acc[4][4] = {};
  const int NT = (kEnd - kBeg) >> 6;
  const int t0 = kBeg >> 6;

  auto stageA = [&](int buf, int kt) {
#pragma unroll
    for (int j = 0; j < 4; ++j) {
      int idx = j * 512 + tid;
      int row = idx >> 3, cp = idx & 7;
      int c = cp ^ (row & 7);
      GLL16(A + (long)(m0 + row) * K + kt * 64 + c * 8,
            &sA[buf][(j * 512 + (wave << 6)) * 8]);
    }
  };
  auto stageB = [&](int buf, int kt) {
#pragma unroll
    for (int j = 0; j < 2; ++j) {
      int idx = j * 512 + tid;
      int row = idx >> 3, cp = idx & 7;
      int c = cp ^ (row & 7);
      GLL16(Bt + (long)(n0 + row) * K + kt * 64 + c * 8,
            &sB[buf][(j * 512 + (wave << 6)) * 8]);
    }
  };

  stageA(0, t0);     stageB(0, t0);
  stageA(1, t0 + 1); stageB(1, t0 + 1);
  asm volatile("s_waitcnt vmcnt(6)" ::: "memory");
  __builtin_amdgcn_s_barrier();

  for (int t = 0; t < NT; ++t) {
    int cur = t & 1;
    bool pf = (t + 2 < NT);
    bf16x8 bf[4][2], af[4][2];

#pragma unroll
    for (int n = 0; n < 4; ++n) {
      int rb = wn + n * 16 + col;
#pragma unroll
      for (int kk = 0; kk < 2; ++kk) {
        int ca = kk * 4 + quad;
        bf[n][kk] = *(const bf16x8*)&sB[cur][rb * 64 + ((ca ^ (rb & 7)) << 3)];
      }
    }
#pragma unroll
    for (int m = 0; m < 4; ++m) {
      int ra = wm + m * 16 + col;
#pragma unroll
      for (int kk = 0; kk < 2; ++kk) {
        int ca = kk * 4 + quad;
        af[m][kk] = *(const bf16x8*)&sA[cur][ra * 64 + ((ca ^ (ra & 7)) << 3)];
      }
    }
    asm volatile("s_waitcnt lgkmcnt(0)" ::: "memory");
    __builtin_amdgcn_s_barrier();        // all waves done reading side cur
    __builtin_amdgcn_sched_barrier(0);   // stages must not hoist above barrier
    if (pf) { stageA(cur, t0 + t + 2); stageB(cur, t0 + t + 2); }
    __builtin_amdgcn_s_setprio(1);
#pragma unroll
    for (int m = 0; m < 4; ++m)
#pragma unroll
      for (int n = 0; n < 4; ++n)
#pragma unroll
        for (int kk = 0; kk < 2; ++kk)
          acc[m][n] = __builtin_amdgcn_mfma_f32_16x16x32_bf16(
              af[m][kk], bf[n][kk], acc[m][n], 0, 0, 0);
    __builtin_amdgcn_s_setprio(0);
    if (pf) asm volatile("s_waitcnt vmcnt(6)" ::: "memory");
    else    asm volatile("s_waitcnt vmcnt(0)" ::: "memory");
    __builtin_amdgcn_s_barrier();        // tile t+1 landed; side swap safe
  }

#pragma unroll
  for (int m = 0; m < 4; ++m) {
#pragma unroll
    for (int n = 0; n < 4; ++n) {
      int Cc = n0 + wn + n * 16 + col;
      float bv = bias ? bias[Cc] : 0.f;
#pragma unroll
      for (int r = 0; r < 4; ++r) {
        int R = m0 + wm + m * 16 + quad * 4 + r;
        out[(long)R * N + Cc] = acc[m][n][r] + bv;
      }
    }
  }
}

// FFN1: [4096,4096,K=1024], relu, bf16 out. grid (16,16).
__global__ __launch_bounds__(512) void g256c_ffn1(
    const short* __restrict__ A, const short* __restrict__ Bt,
    const float* __restrict__ bias, short* __restrict__ out) {
  gemm256c_core<0, true, short>(A, Bt, bias, out, 4096, 1024, 0, 1024,
                                blockIdx.x * 256, blockIdx.y * 256);
}

// QKV: grid (16,4,3); z selects (A, Bt, bias, out); head-split output.
__global__ __launch_bounds__(512) void g256c_qkv(
    const short* __restrict__ Aq, const short* __restrict__ Ak,
    const short* __restrict__ Av, const short* __restrict__ Btq,
    const short* __restrict__ Btk, const short* __restrict__ Btv,
    const float* __restrict__ bq, const float* __restrict__ bk,
    const float* __restrict__ bv, short* __restrict__ Qp,
    short* __restrict__ Kp, short* __restrict__ Vp) {
  int z = blockIdx.z;
  const short* A = z == 0 ? Aq : (z == 1 ? Ak : Av);
  const short* Bt = z == 0 ? Btq : (z == 1 ? Btk : Btv);
  const float* bias = z == 0 ? bq : (z == 1 ? bk : bv);
  short* out = z == 0 ? Qp : (z == 1 ? Kp : Vp);
  gemm256c_core<1, false, short>(A, Bt, bias, out, 1024, 1024, 0, 1024,
                                 blockIdx.x * 256, blockIdx.y * 256);
}

// Wo: [4096,1024,K=1024] split-K=2, BN=128. grid (16,8,2). f32 partials.
__global__ __launch_bounds__(512) void gsp_wo(
    const short* __restrict__ A, const short* __restrict__ Bt,
    const float* __restrict__ bias, float* __restrict__ p0,
    float* __restrict__ p1) {
  int z = blockIdx.z;
  float* out = z == 0 ? p0 : p1;
  const float* b = z == 0 ? bias : nullptr;
  gsp128_core(A, Bt, b, out, 1024, 1024, z * 512, z * 512 + 512,
              blockIdx.x * 256, blockIdx.y * 128);
}

// FFN2: [4096,1024,K=4096] split-K=2, BN=128. grid (16,8,2). f32 partials.
__global__ __launch_bounds__(512) void gsp_ffn2(
    const short* __restrict__ A, const short* __restrict__ Bt,
    const float* __restrict__ bias, float* __restrict__ p0,
    float* __restrict__ p1) {
  int z = blockIdx.z;
  float* out = z == 0 ? p0 : p1;
  const float* b = z == 0 ? bias : nullptr;
  gsp128_core(A, Bt, b, out, 1024, 4096, z * 2048, z * 2048 + 2048,
              blockIdx.x * 256, blockIdx.y * 128);
}

// ---------------------------------------------------------------------------
// Flash attention (R13): 256 thr / 4 waves, q-tile 64.
// Wave (wlow = wave>>1, g = wave&1): q-subtile wlow (32 rows) x key-half g.
// grid (32 bh, 16 pairs); pass 0: qt = pair, pass 1: qt = 31 - pair.
// LDS 48.3KB -> 2 blocks/CU co-resident.
// ---------------------------------------------------------------------------
__global__ __launch_bounds__(256) void attn_kernel(
    const short* __restrict__ Q, const short* __restrict__ K,
    const short* __restrict__ V, const int* __restrict__ maskp,
    short* __restrict__ ctx) {
  __shared__ __align__(16) short sK[2][64 * 64];   // swizzled 8-chunks, 16 KB
  __shared__ __align__(16) int   sVt[2][64 * 32];  // V^T packed pairs, 16 KB
  __shared__ __align__(16) short sP[4 * 32 * 64];  // per-wave P, 16 KB
  __shared__ float sLred[64];                      // cross-g lsum exchange
  int tid = threadIdx.x, wave = tid >> 6;
  int lane = tid & 63;
  int col = lane & 15, quad = lane >> 4;
  int wlow = wave >> 1, g = wave & 1;
  int bh = blockIdx.x, pair = blockIdx.y;
  int maskv = maskp[0];
  const long base = (long)bh * (2048 * 64);
  int b = bh >> 4, h = bh & 15;

  int kp = tid & 31, dg = tid >> 5, d0v = dg * 8;

  for (int pass = 0; pass < 2; ++pass) {
    int qt = pass ? (31 - pair) : pair;
    int iq0 = qt * 64 + wlow * 32;    // wave's first q-row

    long jmax = (long)qt * 64 + 63 + maskv - 1;
    int tot = (jmax < 0) ? 0 : (int)(jmax >> 6) + 1;
    if (tot > 32) tot = 32;

    bf16x8 aQ[2][2];
#pragma unroll
    for (int mt = 0; mt < 2; ++mt)
#pragma unroll
      for (int kk = 0; kk < 2; ++kk)
        aQ[mt][kk] = *(const bf16x8*)&Q[base +
            (long)(iq0 + mt * 16 + col) * 64 + kk * 32 + quad * 8];

    f32x4 o[2][4] = {};
    float lsum[2][4] = {};

    if (tot > 0) {
      // prologue: stage tile 0 into buffer 0
#pragma unroll
      for (int j = 0; j < 2; ++j) {
        int idx = j * 256 + tid;
        int row = idx >> 3, cp = idx & 7;
        int c = cp ^ (row & 7);
        GLL16(K + base + (long)row * 64 + c * 8,
              &sK[0][(j * 256 + (wave << 6)) * 8]);
      }
      {
        s16x8 u0 = *(const s16x8*)&V[base + (long)(2 * kp) * 64 + d0v];
        s16x8 u1 = *(const s16x8*)&V[base + (long)(2 * kp + 1) * 64 + d0v];
#pragma unroll
        for (int j = 0; j < 8; ++j) {
          int d = d0v + j;
          int w = ((int)(unsigned short)u1[j] << 16) | (unsigned short)u0[j];
          sVt[0][d * 32 + ((((kp >> 2) ^ (d & 7)) << 2) | (kp & 3))] = w;
        }
      }
    }
    __syncthreads();

    for (int kt = 0; kt < tot; ++kt) {
      int cur = kt & 1, nxt = cur ^ 1;
      bool pf = (kt + 1 < tot);

      // --- prefetch next tile: K via GLL16, V into registers ---
      s16x8 u0, u1;
      if (pf) {
#pragma unroll
        for (int j = 0; j < 2; ++j) {
          int idx = j * 256 + tid;
          int row = idx >> 3, cp = idx & 7;
          int c = cp ^ (row & 7);
          GLL16(K + base + (long)((kt + 1) * 64 + row) * 64 + c * 8,
                &sK[nxt][(j * 256 + (wave << 6)) * 8]);
        }
        u0 = *(const s16x8*)&V[base + (long)((kt + 1) * 64 + 2 * kp) * 64 + d0v];
        u1 = *(const s16x8*)&V[base + (long)((kt + 1) * 64 + 2 * kp + 1) * 64 + d0v];
      }

      // --- scores: 2 m-tiles x wave's 32 keys (nt local, key = 2g+nt) ---
      f32x4 sc[2][2] = {};
      __builtin_amdgcn_s_setprio(1);
#pragma unroll
      for (int kk = 0; kk < 2; ++kk) {
        int ca = kk * 4 + quad;
#pragma unroll
        for (int nt = 0; nt < 2; ++nt) {
          int rk = (2 * g + nt) * 16 + col;
          bf16x8 bK = *(const bf16x8*)&sK[cur][rk * 64 + ((ca ^ (rk & 7)) << 3)];
#pragma unroll
          for (int mt = 0; mt < 2; ++mt)
            sc[mt][nt] = __builtin_amdgcn_mfma_f32_16x16x32_bf16(
                aQ[mt][kk], bK, sc[mt][nt], 0, 0, 0);
        }
      }
      __builtin_amdgcn_s_setprio(0);

      // --- streaming softmax; diagonal-only masking (per wave) ---
      bool interior = (kt * 64 + g * 32 + 31) < (iq0 + maskv);
      if (interior) {
#pragma unroll
        for (int mt = 0; mt < 2; ++mt)
#pragma unroll
          for (int r = 0; r < 4; ++r) {
            int qr = mt * 16 + quad * 4 + r;
#pragma unroll
            for (int nt = 0; nt < 2; ++nt) {
              float p = EXP2F(sc[mt][nt][r] * SM_SCALE);
              lsum[mt][r] += p;
              int k8 = 4 * g + nt * 2 + (col >> 3);
              sP[wave * 2048 + qr * 64 + (((k8 ^ (qr & 7)) << 3) | (col & 7))] =
                  f2bf_fast(p);
            }
          }
      } else {
#pragma unroll
        for (int mt = 0; mt < 2; ++mt)
#pragma unroll
          for (int r = 0; r < 4; ++r) {
            int i = iq0 + mt * 16 + quad * 4 + r;
            int qr = mt * 16 + quad * 4 + r;
#pragma unroll
            for (int nt = 0; nt < 2; ++nt) {
              int j = kt * 64 + (2 * g + nt) * 16 + col;
              float p = (j < i + maskv) ? EXP2F(sc[mt][nt][r] * SM_SCALE) : 0.f;
              lsum[mt][r] += p;
              int k8 = 4 * g + nt * 2 + (col >> 3);
              sP[wave * 2048 + qr * 64 + (((k8 ^ (qr & 7)) << 3) | (col & 7))] =
                  f2bf_fast(p);
            }
          }
      }

      // --- O += P @ V over wave's 32 keys (sP wave-private, no barrier) ---
      {
        int ca = 4 * g + quad;
        bf16x8 bV[4];
#pragma unroll
        for (int dt = 0; dt < 4; ++dt) {
          int d = dt * 16 + col;
          bV[dt] = *(const bf16x8*)((const short*)sVt[cur] + d * 64 +
                                    ((ca ^ (d & 7)) << 3));
        }
        __builtin_amdgcn_s_setprio(1);
#pragma unroll
        for (int mt = 0; mt < 2; ++mt) {
          int rp = mt * 16 + col;
          bf16x8 aP = *(const bf16x8*)&sP[wave * 2048 + rp * 64 +
                                          ((ca ^ (rp & 7)) << 3)];
#pragma unroll
          for (int dt = 0; dt < 4; ++dt)
            o[mt][dt] = __builtin_amdgcn_mfma_f32_16x16x32_bf16(
                aP, bV[dt], o[mt][dt], 0, 0, 0);
        }
        __builtin_amdgcn_s_setprio(0);
      }

      // --- commit prefetched V into sVt[nxt] ---
      if (pf) {
#pragma unroll
        for (int j = 0; j < 8; ++j) {
          int d = d0v + j;
          int w = ((int)(unsigned short)u1[j] << 16) | (unsigned short)u0[j];
          sVt[nxt][d * 32 + ((((kp >> 2) ^ (d & 7)) << 2) | (kp & 3))] = w;
        }
      }
      __syncthreads();   // drains GLL16 (vmcnt) + V writes before next iter
    }

    // --- epilogue: reduce lsum over the 16 key-lanes (within wave) ---
#pragma unroll
    for (int mt = 0; mt < 2; ++mt)
#pragma unroll
      for (int r = 0; r < 4; ++r)
#pragma unroll
        for (int off = 1; off < 16; off <<= 1)
          lsum[mt][r] += __shfl_xor(lsum[mt][r], off);

    // --- cross-g combine: g=1 dumps O + lsum; g=0 adds and stores. ---
    f32x4* odv = (f32x4*)sP;          // sP dead until next pass
    int slot = wlow * 64 + lane;
    if (g == 1) {
#pragma unroll
      for (int mt = 0; mt < 2; ++mt)
#pragma unroll
        for (int dt = 0; dt < 4; ++dt)
          odv[(mt * 4 + dt) * 128 + slot] = o[mt][dt];
      if (col == 0) {
#pragma unroll
        for (int mt = 0; mt < 2; ++mt)
#pragma unroll
          for (int r = 0; r < 4; ++r)
            sLred[wlow * 32 + mt * 16 + quad * 4 + r] = lsum[mt][r];
      }
    }
    __syncthreads();
    if (g == 0) {
#pragma unroll
      for (int mt = 0; mt < 2; ++mt)
#pragma unroll
        for (int dt = 0; dt < 4; ++dt)
          o[mt][dt] += odv[(mt * 4 + dt) * 128 + slot];
#pragma unroll
      for (int mt = 0; mt < 2; ++mt)
#pragma unroll
        for (int r = 0; r < 4; ++r) {
          float ls = lsum[mt][r] + sLred[wlow * 32 + mt * 16 + quad * 4 + r];
          int i = iq0 + mt * 16 + quad * 4 + r;
          float inv = (ls > 0.f) ? 1.f / ls : 0.f;
          if (maskv == 0 && i == 0) inv = 0.f;
#pragma unroll
          for (int dt = 0; dt < 4; ++dt)
            ctx[(long)(b * 2048 + i) * 1024 + h * 64 + dt * 16 + col] =
                f2bf(o[mt][dt][r] * inv);
        }
    }
    __syncthreads();   // O-dump reads done before next pass reuses sP/sK/sVt
  }
}

// ---------------------------------------------------------------------------
// LayerNorm over last dim (1024) of (p0 + p1 + res). One block per row.
// ---------------------------------------------------------------------------
__global__ __launch_bounds__(256) void ln_comb_kernel(
    const float* __restrict__ p0, const float* __restrict__ p1,
    const float* __restrict__ res, const float* __restrict__ g,
    const float* __restrict__ b, float* __restrict__ outf,
    short* __restrict__ outb) {
  int r = blockIdx.x, tid = threadIdx.x;
  int lane = tid & 63, wave = tid >> 6;
  long off0 = (long)r * 1024;
  F4 a = ((const F4*)(p0 + off0))[tid];
  F4 c = ((const F4*)(p1 + off0))[tid];
  F4 d = ((const F4*)(res + off0))[tid];
  F4 v = { a.x + c.x + d.x, a.y + c.y + d.y, a.z + c.z + d.z, a.w + c.w + d.w };
  float s = v.x + v.y + v.z + v.w;
  float sq = v.x * v.x + v.y * v.y + v.z * v.z + v.w * v.w;
#pragma unroll
  for (int off = 1; off < 64; off <<= 1) {
    s += __shfl_xor(s, off);
    sq += __shfl_xor(sq, off);
  }
  __shared__ float rs[4], rq[4];
  if (lane == 0) { rs[wave] = s; rq[wave] = sq; }
  __syncthreads();
  s = rs[0] + rs[1] + rs[2] + rs[3];
  sq = rq[0] + rq[1] + rq[2] + rq[3];
  float mu = s * (1.0f / 1024.0f);
  float var = sq * (1.0f / 1024.0f) - mu * mu;
  float rstd = rsqrtf(var + 1e-5f);
  F4 gv = ((const F4*)g)[tid], bv = ((const F4*)b)[tid];
  F4 o;
  o.x = (v.x - mu) * rstd * gv.x + bv.x;
  o.y = (v.y - mu) * rstd * gv.y + bv.y;
  o.z = (v.z - mu) * rstd * gv.z + bv.z;
  o.w = (v.w - mu) * rstd * gv.w + bv.w;
  ((F4*)(outf + off0))[tid] = o;
  if (outb) {
    S4 ob = { f2bf(o.x), f2bf(o.y), f2bf(o.z), f2bf(o.w) };
    ((S4*)(outb + off0))[tid] = ob;
  }
}

// ---------------------------------------------------------------------------
extern "C" void kernel_launch(void* const* d_in, const int* in_sizes, int n_in,
                              void* d_out, int out_size, void* d_ws, size_t ws_size,
                              hipStream_t stream) {
  const float* query  = (const float*)d_in[0];
  const float* keyi   = (const float*)d_in[1];
  const float* values = (const float*)d_in[2];
  const float* Wq = (const float*)d_in[3];
  const float* bq = (const float*)d_in[4];
  const float* Wk = (const float*)d_in[5];
  const float* bk = (const float*)d_in[6];
  const float* Wv = (const float*)d_in[7];
  const float* bv = (const float*)d_in[8];
  const float* Wo = (const float*)d_in[9];
  const float* bo = (const float*)d_in[10];
  const float* ln1_g = (const float*)d_in[11];
  const float* ln1_b = (const float*)d_in[12];
  const float* W1 = (const float*)d_in[13];
  const float* b1 = (const float*)d_in[14];
  const float* W2 = (const float*)d_in[15];
  const float* b2 = (const float*)d_in[16];
  const float* ln2_g = (const float*)d_in[17];
  const float* ln2_b = (const float*)d_in[18];
  const int*   maskp = (const int*)d_in[19];
  float* out = (float*)d_out;

  char* ws = (char*)d_ws;
  const size_t MB = 1u << 20;
  // Layout (liveness-checked overlays):
  short* q_bf = (short*)(ws + 0);        // 0..8    dead after QKV
  short* k_bf = (short*)(ws + 8 * MB);   // 8..16   dead after QKV
  short* v_bf = (short*)(ws + 16 * MB);  // 16..24  dead after QKV
  short* ctx  = (short*)(ws + 24 * MB);  // 24..32  attn out, dead after Wo
  short* Qp   = (short*)(ws + 32 * MB);  // 32..40  dead after attn
  short* Kp   = (short*)(ws + 40 * MB);  // 40..48  dead after attn
  short* Vp   = (short*)(ws + 48 * MB);  // 48..56  dead after attn
  short* Wqt  = (short*)(ws + 56 * MB);  // 56..58
  short* Wkt  = (short*)(ws + 58 * MB);  // 58..60
  short* Wvt  = (short*)(ws + 60 * MB);  // 60..62
  short* Wot  = (short*)(ws + 62 * MB);  // 62..64
  short* W1t  = (short*)(ws + 64 * MB);  // 64..72
  short* W2t  = (short*)(ws + 72 * MB);  // 72..80
  short* hbuf = (short*)(ws + 80 * MB);  // 80..112 FFN1 out
  // Wo partials: live Wo-gemm -> LN1 (q/k/v_bf, Qp/Kp dead by then)
  float* pWo0 = (float*)(ws + 0);        // 0..16
  float* pWo1 = (float*)(ws + 32 * MB);  // 32..48
  float* x_f32 = (float*)(ws + 16 * MB); // 16..32  LN1 out (v_bf/ctx dead)
  short* x_bf  = (short*)(ws + 48 * MB); // 48..56  LN1 out (Vp dead)
  // FFN2 partials: live FFN2 -> LN2 (pWo dead after LN1)
  float* pF0 = (float*)(ws + 0);         // 0..16
  float* pF1 = (float*)(ws + 32 * MB);   // 32..48

  // 1. activations -> bf16 (one dispatch)
  cvt_bf16_kernel<<<dim3(4096, 3), 256, 0, stream>>>(query, keyi, values,
                                                     q_bf, k_bf, v_bf);
  // 2. all weights -> transposed bf16 [N,K] (one dispatch)
  transpose_cvt_kernel<<<3072, 256, 0, stream>>>(Wq, Wk, Wv, Wo, W1, W2,
                                                 Wqt, Wkt, Wvt, Wot, W1t, W2t);
  // 3. fused QKV projections -> [B,H,S,64] bf16 (192 blocks)
  g256c_qkv<<<dim3(16, 4, 3), 512, 0, stream>>>(q_bf, k_bf, v_bf,
                                                Wqt, Wkt, Wvt,
                                                bq, bk, bv, Qp, Kp, Vp);
  // 4. flash attention (key-split, 512 blocks co-resident 2/CU) -> ctx
  attn_kernel<<<dim3(32, 16), 256, 0, stream>>>(Qp, Kp, Vp, maskp, ctx);
  // 5. output projection, split-K=2, BN=128 (256 blocks) -> partials
  gsp_wo<<<dim3(16, 8, 2), 512, 0, stream>>>(ctx, Wot, bo, pWo0, pWo1);
  // 6. LN1(p0+p1+query) -> x (f32 + bf16)
  ln_comb_kernel<<<4096, 256, 0, stream>>>(pWo0, pWo1, query, ln1_g, ln1_b,
                                           x_f32, x_bf);
  // 7. FFN1 (+relu) -> h bf16 [4096,4096] (256 blocks)
  g256c_ffn1<<<dim3(16, 16), 512, 0, stream>>>(x_bf, W1t, b1, hbuf);
  // 8. FFN2, split-K=2, BN=128 (256 blocks) -> partials
  gsp_ffn2<<<dim3(16, 8, 2), 512, 0, stream>>>(hbuf, W2t, b2, pF0, pF1);
  // 9. LN2(p0+p1+x) -> out f32
  ln_comb_kernel<<<4096, 256, 0, stream>>>(pF0, pF1, x_f32, ln2_g, ln2_b,
                                           out, nullptr);

  (void)in_sizes; (void)n_in; (void)out_size; (void)ws_size;
}

// Round 10
// 362.825 us; speedup vs baseline: 1.0547x; 1.0209x over previous
//
#include <hip/hip_runtime.h>

// ---------------------------------------------------------------------------
// TransformerLayer on MI355X (gfx950), bf16-MFMA pipeline.
// B=2, S=2048, D_MODEL=1024, N_HEADS=16, D_K=64, D_FF=4096, mask=0 (runtime).
// R15: ALL GEMMs -> gsp128b: BM=BN=128, 256 thr / 4 waves (2m x 2n, 64x64
//      per wave), collapsed 2-barrier K-loop, dbuf 64KB LDS -> 2 independent
//      blocks/CU (barrier convoys covered by the co-resident block).
//      cvt+transpose merged into one dispatch. Attn/LN unchanged from R13.
// ---------------------------------------------------------------------------

typedef __attribute__((ext_vector_type(8))) __bf16 bf16x8;
typedef __attribute__((ext_vector_type(4))) float f32x4;
typedef __attribute__((ext_vector_type(8))) short s16x8;

struct alignas(8)  S4 { short x, y, z, w; };
struct alignas(16) F4 { float x, y, z, w; };

static __device__ __forceinline__ short f2bf(float f) {
  unsigned u = __float_as_uint(f);
  u += 0x7fff + ((u >> 16) & 1);   // RTNE
  return (short)(u >> 16);
}

// native f32->bf16 (v_cvt, RTNE)
static __device__ __forceinline__ short f2bf_fast(float f) {
  union { __bf16 h; short s; } u;
  u.h = (__bf16)f;
  return u.s;
}

#if __has_builtin(__builtin_amdgcn_exp2f)
#define EXP2F(x) __builtin_amdgcn_exp2f(x)
#else
#define EXP2F(x) exp2f(x)
#endif
// 0.125 (1/sqrt(dk)) * log2(e)
#define SM_SCALE 0.18033688011112042f

static __device__ __forceinline__ void store_out(float* p, float v) { *p = v; }
static __device__ __forceinline__ void store_out(short* p, float v) { *p = f2bf(v); }

// async global->LDS, 16B per lane; LDS dest = wave-uniform base + lane*16
#define GLL16(g, l)                                                         \
  __builtin_amdgcn_global_load_lds(                                         \
      (__attribute__((address_space(1))) void*)(g),                         \
      (__attribute__((address_space(3))) void*)(l), 16, 0, 0)

// ---------------------------------------------------------------------------
// Merged pre-pass: blocks 0..12287 = f32->bf16 convert of q/k/v activations
// (3 x 4096 blocks); blocks 12288..15359 = weight transpose W[K,N]->Wt[N,K].
// ---------------------------------------------------------------------------
__global__ __launch_bounds__(256) void prep_kernel(
    const float* __restrict__ i0, const float* __restrict__ i1,
    const float* __restrict__ i2, short* __restrict__ o0,
    short* __restrict__ o1, short* __restrict__ o2,
    const float* __restrict__ Wq, const float* __restrict__ Wk,
    const float* __restrict__ Wv, const float* __restrict__ Wo,
    const float* __restrict__ W1, const float* __restrict__ W2,
    short* __restrict__ Wqt, short* __restrict__ Wkt,
    short* __restrict__ Wvt, short* __restrict__ Wot,
    short* __restrict__ W1t, short* __restrict__ W2t) {
  __shared__ float tile[64][65];
  int bid0 = blockIdx.x;
  int tid = threadIdx.x;
  if (bid0 < 12288) {
    int z = bid0 >> 12, x = bid0 & 4095;
    const float* in = z == 0 ? i0 : (z == 1 ? i1 : i2);
    short* out = z == 0 ? o0 : (z == 1 ? o1 : o2);
    int i = (x * 256 + tid) * 4;
    F4 v = *(const F4*)(in + i);
    S4 o = { f2bf(v.x), f2bf(v.y), f2bf(v.z), f2bf(v.w) };
    *(S4*)(out + i) = o;
    return;
  }
  int bid = bid0 - 12288;
  const float* W; short* Wt; int K, N, kx, ny;
  if (bid < 1024) {
    int w = bid >> 8, t = bid & 255;
    W = w == 0 ? Wq : (w == 1 ? Wk : (w == 2 ? Wv : Wo));
    Wt = w == 0 ? Wqt : (w == 1 ? Wkt : (w == 2 ? Wvt : Wot));
    K = 1024; N = 1024; kx = t & 15; ny = t >> 4;
  } else if (bid < 2048) {
    int t = bid - 1024;
    W = W1; Wt = W1t; K = 1024; N = 4096; kx = t & 15; ny = t >> 4;
  } else {
    int t = bid - 2048;
    W = W2; Wt = W2t; K = 4096; N = 1024; kx = t & 63; ny = t >> 6;
  }
  int k0 = kx * 64, n0 = ny * 64;
  int rr = tid >> 4, cc = (tid & 15) * 4;
#pragma unroll
  for (int p = 0; p < 4; ++p) {
    int row = p * 16 + rr;
    F4 v = *(const F4*)&W[(long)(k0 + row) * N + n0 + cc];
    tile[row][cc] = v.x; tile[row][cc + 1] = v.y;
    tile[row][cc + 2] = v.z; tile[row][cc + 3] = v.w;
  }
  __syncthreads();
#pragma unroll
  for (int p = 0; p < 4; ++p) {
    int rn = p * 16 + rr;
    S4 o = { f2bf(tile[cc + 0][rn]), f2bf(tile[cc + 1][rn]),
             f2bf(tile[cc + 2][rn]), f2bf(tile[cc + 3][rn]) };
    *(S4*)&Wt[(long)(n0 + rn) * K + k0 + cc] = o;
  }
}

// ---------------------------------------------------------------------------
// gsp128b (R15 core, ALL GEMMs): BM=128, BN=128, BK=64, 256 thr / 4 waves
// as 2m x 2n (64x64 per wave, MFMA:ds_read = 32:16). LDS 64KB -> 2 blocks/CU.
// Collapsed K-loop: {read 16 frags; lgkm(0); barrier; stage t+2 (8 GLL16);
// setprio + 32 MFMA; vmcnt(8) counted; barrier} = 2 barriers/tile.
// OUT_MODE 0: row-major [M,N].  OUT_MODE 1: [B,H,S,64] head split (N==1024).
// ---------------------------------------------------------------------------
template <int OUT_MODE, bool RELU, typename OT>
__device__ __forceinline__ void gsp128b_core(
    const short* __restrict__ A, const short* __restrict__ Bt,
    const float* __restrict__ bias, OT* __restrict__ out,
    int N, int K, int kBeg, int kEnd, int m0, int n0) {
  __shared__ __align__(16) short sA[2][128 * 64];
  __shared__ __align__(16) short sB[2][128 * 64];
  int tid = threadIdx.x;
  int lane = tid & 63, wave = tid >> 6;
  int col = lane & 15, quad = lane >> 4;
  int wm = (wave >> 1) * 64;   // 2 m-groups of 64 rows
  int wn = (wave & 1) * 64;    // 2 n-groups of 64 cols

  f32x4 acc[4][4] = {};
  const int NT = (kEnd - kBeg) >> 6;
  const int t0 = kBeg >> 6;

  // stage: 128 rows x 8 chunks = 1024 chunks; 4 rounds x 256 thr
  auto stageA = [&](int buf, int kt) {
#pragma unroll
    for (int j = 0; j < 4; ++j) {
      int idx = j * 256 + tid;
      int row = idx >> 3, cp = idx & 7;
      int c = cp ^ (row & 7);
      GLL16(A + (long)(m0 + row) * K + kt * 64 + c * 8,
            &sA[buf][(j * 256 + (wave << 6)) * 8]);
    }
  };
  auto stageB = [&](int buf, int kt) {
#pragma unroll
    for (int j = 0; j < 4; ++j) {
      int idx = j * 256 + tid;
      int row = idx >> 3, cp = idx & 7;
      int c = cp ^ (row & 7);
      GLL16(Bt + (long)(n0 + row) * K + kt * 64 + c * 8,
            &sB[buf][(j * 256 + (wave << 6)) * 8]);
    }
  };

  // prologue: stage tiles 0,1 (16 loads); drain tile 0 (leave tile 1's 8)
  stageA(0, t0);     stageB(0, t0);
  stageA(1, t0 + 1); stageB(1, t0 + 1);
  asm volatile("s_waitcnt vmcnt(8)" ::: "memory");
  __builtin_amdgcn_s_barrier();

  for (int t = 0; t < NT; ++t) {
    int cur = t & 1;
    bool pf = (t + 2 < NT);
    bf16x8 bf[4][2], af[4][2];

    // read all fragments of tile t (8 A + 8 B ds_read_b128)
#pragma unroll
    for (int n = 0; n < 4; ++n) {
      int rb = wn + n * 16 + col;
#pragma unroll
      for (int kk = 0; kk < 2; ++kk) {
        int ca = kk * 4 + quad;
        bf[n][kk] = *(const bf16x8*)&sB[cur][rb * 64 + ((ca ^ (rb & 7)) << 3)];
      }
    }
#pragma unroll
    for (int m = 0; m < 4; ++m) {
      int ra = wm + (m & 1) * 16 + (m >> 1) * 32 + col;
      // rows wm + {0,16,32,48}: order m0=+0, m1=+16, m2=+32, m3=+48
#pragma unroll
      for (int kk = 0; kk < 2; ++kk) {
        int ca = kk * 4 + quad;
        af[m][kk] = *(const bf16x8*)&sA[cur][ra * 64 + ((ca ^ (ra & 7)) << 3)];
      }
    }
    asm volatile("s_waitcnt lgkmcnt(0)" ::: "memory");
    __builtin_amdgcn_s_barrier();        // all waves done reading side cur
    __builtin_amdgcn_sched_barrier(0);   // stages must not hoist above barrier
    if (pf) { stageA(cur, t0 + t + 2); stageB(cur, t0 + t + 2); }
    __builtin_amdgcn_s_setprio(1);
#pragma unroll
    for (int m = 0; m < 4; ++m)
#pragma unroll
      for (int n = 0; n < 4; ++n)
#pragma unroll
        for (int kk = 0; kk < 2; ++kk)
          acc[m][n] = __builtin_amdgcn_mfma_f32_16x16x32_bf16(
              af[m][kk], bf[n][kk], acc[m][n], 0, 0, 0);
    __builtin_amdgcn_s_setprio(0);
    if (pf) asm volatile("s_waitcnt vmcnt(8)" ::: "memory");
    else    asm volatile("s_waitcnt vmcnt(0)" ::: "memory");
    __builtin_amdgcn_s_barrier();        // tile t+1 landed; side swap safe
  }

  // epilogue: C/D layout col=lane&15, row=quad*4+reg
#pragma unroll
  for (int m = 0; m < 4; ++m) {
    int rbase = wm + (m & 1) * 16 + (m >> 1) * 32;
#pragma unroll
    for (int n = 0; n < 4; ++n) {
      int Cc = n0 + wn + n * 16 + col;
      float bv = bias ? bias[Cc] : 0.f;
#pragma unroll
      for (int r = 0; r < 4; ++r) {
        int R = m0 + rbase + quad * 4 + r;
        float v = acc[m][n][r] + bv;
        if (RELU) v = v > 0.f ? v : 0.f;
        if (OUT_MODE == 0) {
          store_out(&out[(long)R * N + Cc], v);
        } else {
          int bb = R >> 11, s = R & 2047, h = Cc >> 6, d = Cc & 63;
          store_out(&out[((long)((bb * 16 + h) * 2048 + s) << 6) + d], v);
        }
      }
    }
  }
}

// QKV: grid (32,8,3); z selects (A, Bt, bias, out); head-split output.
__global__ __launch_bounds__(256) void gsp_qkv(
    const short* __restrict__ Aq, const short* __restrict__ Ak,
    const short* __restrict__ Av, const short* __restrict__ Btq,
    const short* __restrict__ Btk, const short* __restrict__ Btv,
    const float* __restrict__ bq, const float* __restrict__ bk,
    const float* __restrict__ bv, short* __restrict__ Qp,
    short* __restrict__ Kp, short* __restrict__ Vp) {
  int z = blockIdx.z;
  const short* A = z == 0 ? Aq : (z == 1 ? Ak : Av);
  const short* Bt = z == 0 ? Btq : (z == 1 ? Btk : Btv);
  const float* bias = z == 0 ? bq : (z == 1 ? bk : bv);
  short* out = z == 0 ? Qp : (z == 1 ? Kp : Vp);
  gsp128b_core<1, false, short>(A, Bt, bias, out, 1024, 1024, 0, 1024,
                                blockIdx.x * 128, blockIdx.y * 128);
}

// Wo: [4096,1024,K=1024] split-K=2. grid (32,8,2). f32 partials.
__global__ __launch_bounds__(256) void gsp_wo(
    const short* __restrict__ A, const short* __restrict__ Bt,
    const float* __restrict__ bias, float* __restrict__ p0,
    float* __restrict__ p1) {
  int z = blockIdx.z;
  float* out = z == 0 ? p0 : p1;
  const float* b = z == 0 ? bias : nullptr;
  gsp128b_core<0, false, float>(A, Bt, b, out, 1024, 1024,
                                z * 512, z * 512 + 512,
                                blockIdx.x * 128, blockIdx.y * 128);
}

// FFN1: [4096,4096,K=1024], relu, bf16 out. grid (32,32).
__global__ __launch_bounds__(256) void gsp_ffn1(
    const short* __restrict__ A, const short* __restrict__ Bt,
    const float* __restrict__ bias, short* __restrict__ out) {
  gsp128b_core<0, true, short>(A, Bt, bias, out, 4096, 1024, 0, 1024,
                               blockIdx.x * 128, blockIdx.y * 128);
}

// FFN2: [4096,1024,K=4096] split-K=2. grid (32,8,2). f32 partials.
__global__ __launch_bounds__(256) void gsp_ffn2(
    const short* __restrict__ A, const short* __restrict__ Bt,
    const float* __restrict__ bias, float* __restrict__ p0,
    float* __restrict__ p1) {
  int z = blockIdx.z;
  float* out = z == 0 ? p0 : p1;
  const float* b = z == 0 ? bias : nullptr;
  gsp128b_core<0, false, float>(A, Bt, b, out, 1024, 4096,
                                z * 2048, z * 2048 + 2048,
                                blockIdx.x * 128, blockIdx.y * 128);
}

// ---------------------------------------------------------------------------
// Flash attention (R13): 256 thr / 4 waves, q-tile 64.
// Wave (wlow = wave>>1, g = wave&1): q-subtile wlow (32 rows) x key-half g.
// grid (32 bh, 16 pairs); pass 0: qt = pair, pass 1: qt = 31 - pair.
// LDS 48.3KB -> 2 blocks/CU co-resident.
// ---------------------------------------------------------------------------
__global__ __launch_bounds__(256) void attn_kernel(
    const short* __restrict__ Q, const short* __restrict__ K,
    const short* __restrict__ V, const int* __restrict__ maskp,
    short* __restrict__ ctx) {
  __shared__ __align__(16) short sK[2][64 * 64];   // swizzled 8-chunks, 16 KB
  __shared__ __align__(16) int   sVt[2][64 * 32];  // V^T packed pairs, 16 KB
  __shared__ __align__(16) short sP[4 * 32 * 64];  // per-wave P, 16 KB
  __shared__ float sLred[64];                      // cross-g lsum exchange
  int tid = threadIdx.x, wave = tid >> 6;
  int lane = tid & 63;
  int col = lane & 15, quad = lane >> 4;
  int wlow = wave >> 1, g = wave & 1;
  int bh = blockIdx.x, pair = blockIdx.y;
  int maskv = maskp[0];
  const long base = (long)bh * (2048 * 64);
  int b = bh >> 4, h = bh & 15;

  int kp = tid & 31, dg = tid >> 5, d0v = dg * 8;

  for (int pass = 0; pass < 2; ++pass) {
    int qt = pass ? (31 - pair) : pair;
    int iq0 = qt * 64 + wlow * 32;    // wave's first q-row

    long jmax = (long)qt * 64 + 63 + maskv - 1;
    int tot = (jmax < 0) ? 0 : (int)(jmax >> 6) + 1;
    if (tot > 32) tot = 32;

    bf16x8 aQ[2][2];
#pragma unroll
    for (int mt = 0; mt < 2; ++mt)
#pragma unroll
      for (int kk = 0; kk < 2; ++kk)
        aQ[mt][kk] = *(const bf16x8*)&Q[base +
            (long)(iq0 + mt * 16 + col) * 64 + kk * 32 + quad * 8];

    f32x4 o[2][4] = {};
    float lsum[2][4] = {};

    if (tot > 0) {
      // prologue: stage tile 0 into buffer 0
#pragma unroll
      for (int j = 0; j < 2; ++j) {
        int idx = j * 256 + tid;
        int row = idx >> 3, cp = idx & 7;
        int c = cp ^ (row & 7);
        GLL16(K + base + (long)row * 64 + c * 8,
              &sK[0][(j * 256 + (wave << 6)) * 8]);
      }
      {
        s16x8 u0 = *(const s16x8*)&V[base + (long)(2 * kp) * 64 + d0v];
        s16x8 u1 = *(const s16x8*)&V[base + (long)(2 * kp + 1) * 64 + d0v];
#pragma unroll
        for (int j = 0; j < 8; ++j) {
          int d = d0v + j;
          int w = ((int)(unsigned short)u1[j] << 16) | (unsigned short)u0[j];
          sVt[0][d * 32 + ((((kp >> 2) ^ (d & 7)) << 2) | (kp & 3))] = w;
        }
      }
    }
    __syncthreads();

    for (int kt = 0; kt < tot; ++kt) {
      int cur = kt & 1, nxt = cur ^ 1;
      bool pf = (kt + 1 < tot);

      // --- prefetch next tile: K via GLL16, V into registers ---
      s16x8 u0, u1;
      if (pf) {
#pragma unroll
        for (int j = 0; j < 2; ++j) {
          int idx = j * 256 + tid;
          int row = idx >> 3, cp = idx & 7;
          int c = cp ^ (row & 7);
          GLL16(K + base + (long)((kt + 1) * 64 + row) * 64 + c * 8,
                &sK[nxt][(j * 256 + (wave << 6)) * 8]);
        }
        u0 = *(const s16x8*)&V[base + (long)((kt + 1) * 64 + 2 * kp) * 64 + d0v];
        u1 = *(const s16x8*)&V[base + (long)((kt + 1) * 64 + 2 * kp + 1) * 64 + d0v];
      }

      // --- scores: 2 m-tiles x wave's 32 keys (nt local, key = 2g+nt) ---
      f32x4 sc[2][2] = {};
      __builtin_amdgcn_s_setprio(1);
#pragma unroll
      for (int kk = 0; kk < 2; ++kk) {
        int ca = kk * 4 + quad;
#pragma unroll
        for (int nt = 0; nt < 2; ++nt) {
          int rk = (2 * g + nt) * 16 + col;
          bf16x8 bK = *(const bf16x8*)&sK[cur][rk * 64 + ((ca ^ (rk & 7)) << 3)];
#pragma unroll
          for (int mt = 0; mt < 2; ++mt)
            sc[mt][nt] = __builtin_amdgcn_mfma_f32_16x16x32_bf16(
                aQ[mt][kk], bK, sc[mt][nt], 0, 0, 0);
        }
      }
      __builtin_amdgcn_s_setprio(0);

      // --- streaming softmax; diagonal-only masking (per wave) ---
      bool interior = (kt * 64 + g * 32 + 31) < (iq0 + maskv);
      if (interior) {
#pragma unroll
        for (int mt = 0; mt < 2; ++mt)
#pragma unroll
          for (int r = 0; r < 4; ++r) {
            int qr = mt * 16 + quad * 4 + r;
#pragma unroll
            for (int nt = 0; nt < 2; ++nt) {
              float p = EXP2F(sc[mt][nt][r] * SM_SCALE);
              lsum[mt][r] += p;
              int k8 = 4 * g + nt * 2 + (col >> 3);
              sP[wave * 2048 + qr * 64 + (((k8 ^ (qr & 7)) << 3) | (col & 7))] =
                  f2bf_fast(p);
            }
          }
      } else {
#pragma unroll
        for (int mt = 0; mt < 2; ++mt)
#pragma unroll
          for (int r = 0; r < 4; ++r) {
            int i = iq0 + mt * 16 + quad * 4 + r;
            int qr = mt * 16 + quad * 4 + r;
#pragma unroll
            for (int nt = 0; nt < 2; ++nt) {
              int j = kt * 64 + (2 * g + nt) * 16 + col;
              float p = (j < i + maskv) ? EXP2F(sc[mt][nt][r] * SM_SCALE) : 0.f;
              lsum[mt][r] += p;
              int k8 = 4 * g + nt * 2 + (col >> 3);
              sP[wave * 2048 + qr * 64 + (((k8 ^ (qr & 7)) << 3) | (col & 7))] =
                  f2bf_fast(p);
            }
          }
      }

      // --- O += P @ V over wave's 32 keys (sP wave-private, no barrier) ---
      {
        int ca = 4 * g + quad;
        bf16x8 bV[4];
#pragma unroll
        for (int dt = 0; dt < 4; ++dt) {
          int d = dt * 16 + col;
          bV[dt] = *(const bf16x8*)((const short*)sVt[cur] + d * 64 +
                                    ((ca ^ (d & 7)) << 3));
        }
        __builtin_amdgcn_s_setprio(1);
#pragma unroll
        for (int mt = 0; mt < 2; ++mt) {
          int rp = mt * 16 + col;
          bf16x8 aP = *(const bf16x8*)&sP[wave * 2048 + rp * 64 +
                                          ((ca ^ (rp & 7)) << 3)];
#pragma unroll
          for (int dt = 0; dt < 4; ++dt)
            o[mt][dt] = __builtin_amdgcn_mfma_f32_16x16x32_bf16(
                aP, bV[dt], o[mt][dt], 0, 0, 0);
        }
        __builtin_amdgcn_s_setprio(0);
      }

      // --- commit prefetched V into sVt[nxt] ---
      if (pf) {
#pragma unroll
        for (int j = 0; j < 8; ++j) {
          int d = d0v + j;
          int w = ((int)(unsigned short)u1[j] << 16) | (unsigned short)u0[j];
          sVt[nxt][d * 32 + ((((kp >> 2) ^ (d & 7)) << 2) | (kp & 3))] = w;
        }
      }
      __syncthreads();   // drains GLL16 (vmcnt) + V writes before next iter
    }

    // --- epilogue: reduce lsum over the 16 key-lanes (within wave) ---
#pragma unroll
    for (int mt = 0; mt < 2; ++mt)
#pragma unroll
      for (int r = 0; r < 4; ++r)
#pragma unroll
        for (int off = 1; off < 16; off <<= 1)
          lsum[mt][r] += __shfl_xor(lsum[mt][r], off);

    // --- cross-g combine: g=1 dumps O + lsum; g=0 adds and stores. ---
    f32x4* odv = (f32x4*)sP;          // sP dead until next pass
    int slot = wlow * 64 + lane;
    if (g == 1) {
#pragma unroll
      for (int mt = 0; mt < 2; ++mt)
#pragma unroll
        for (int dt = 0; dt < 4; ++dt)
          odv[(mt * 4 + dt) * 128 + slot] = o[mt][dt];
      if (col == 0) {
#pragma unroll
        for (int mt = 0; mt < 2; ++mt)
#pragma unroll
          for (int r = 0; r < 4; ++r)
            sLred[wlow * 32 + mt * 16 + quad * 4 + r] = lsum[mt][r];
      }
    }
    __syncthreads();
    if (g == 0) {
#pragma unroll
      for (int mt = 0; mt < 2; ++mt)
#pragma unroll
        for (int dt = 0; dt < 4; ++dt)
          o[mt][dt] += odv[(mt * 4 + dt) * 128 + slot];
#pragma unroll
      for (int mt = 0; mt < 2; ++mt)
#pragma unroll
        for (int r = 0; r < 4; ++r) {
          float ls = lsum[mt][r] + sLred[wlow * 32 + mt * 16 + quad * 4 + r];
          int i = iq0 + mt * 16 + quad * 4 + r;
          float inv = (ls > 0.f) ? 1.f / ls : 0.f;
          if (maskv == 0 && i == 0) inv = 0.f;
#pragma unroll
          for (int dt = 0; dt < 4; ++dt)
            ctx[(long)(b * 2048 + i) * 1024 + h * 64 + dt * 16 + col] =
                f2bf(o[mt][dt][r] * inv);
        }
    }
    __syncthreads();   // O-dump reads done before next pass reuses sP/sK/sVt
  }
}

// ---------------------------------------------------------------------------
// LayerNorm over last dim (1024) of (p0 + p1 + res). One block per row.
// ---------------------------------------------------------------------------
__global__ __launch_bounds__(256) void ln_comb_kernel(
    const float* __restrict__ p0, const float* __restrict__ p1,
    const float* __restrict__ res, const float* __restrict__ g,
    const float* __restrict__ b, float* __restrict__ outf,
    short* __restrict__ outb) {
  int r = blockIdx.x, tid = threadIdx.x;
  int lane = tid & 63, wave = tid >> 6;
  long off0 = (long)r * 1024;
  F4 a = ((const F4*)(p0 + off0))[tid];
  F4 c = ((const F4*)(p1 + off0))[tid];
  F4 d = ((const F4*)(res + off0))[tid];
  F4 v = { a.x + c.x + d.x, a.y + c.y + d.y, a.z + c.z + d.z, a.w + c.w + d.w };
  float s = v.x + v.y + v.z + v.w;
  float sq = v.x * v.x + v.y * v.y + v.z * v.z + v.w * v.w;
#pragma unroll
  for (int off = 1; off < 64; off <<= 1) {
    s += __shfl_xor(s, off);
    sq += __shfl_xor(sq, off);
  }
  __shared__ float rs[4], rq[4];
  if (lane == 0) { rs[wave] = s; rq[wave] = sq; }
  __syncthreads();
  s = rs[0] + rs[1] + rs[2] + rs[3];
  sq = rq[0] + rq[1] + rq[2] + rq[3];
  float mu = s * (1.0f / 1024.0f);
  float var = sq * (1.0f / 1024.0f) - mu * mu;
  float rstd = rsqrtf(var + 1e-5f);
  F4 gv = ((const F4*)g)[tid], bv = ((const F4*)b)[tid];
  F4 o;
  o.x = (v.x - mu) * rstd * gv.x + bv.x;
  o.y = (v.y - mu) * rstd * gv.y + bv.y;
  o.z = (v.z - mu) * rstd * gv.z + bv.z;
  o.w = (v.w - mu) * rstd * gv.w + bv.w;
  ((F4*)(outf + off0))[tid] = o;
  if (outb) {
    S4 ob = { f2bf(o.x), f2bf(o.y), f2bf(o.z), f2bf(o.w) };
    ((S4*)(outb + off0))[tid] = ob;
  }
}

// ---------------------------------------------------------------------------
extern "C" void kernel_launch(void* const* d_in, const int* in_sizes, int n_in,
                              void* d_out, int out_size, void* d_ws, size_t ws_size,
                              hipStream_t stream) {
  const float* query  = (const float*)d_in[0];
  const float* keyi   = (const float*)d_in[1];
  const float* values = (const float*)d_in[2];
  const float* Wq = (const float*)d_in[3];
  const float* bq = (const float*)d_in[4];
  const float* Wk = (const float*)d_in[5];
  const float* bk = (const float*)d_in[6];
  const float* Wv = (const float*)d_in[7];
  const float* bv = (const float*)d_in[8];
  const float* Wo = (const float*)d_in[9];
  const float* bo = (const float*)d_in[10];
  const float* ln1_g = (const float*)d_in[11];
  const float* ln1_b = (const float*)d_in[12];
  const float* W1 = (const float*)d_in[13];
  const float* b1 = (const float*)d_in[14];
  const float* W2 = (const float*)d_in[15];
  const float* b2 = (const float*)d_in[16];
  const float* ln2_g = (const float*)d_in[17];
  const float* ln2_b = (const float*)d_in[18];
  const int*   maskp = (const int*)d_in[19];
  float* out = (float*)d_out;

  char* ws = (char*)d_ws;
  const size_t MB = 1u << 20;
  // Layout (liveness-checked overlays):
  short* q_bf = (short*)(ws + 0);        // 0..8    dead after QKV
  short* k_bf = (short*)(ws + 8 * MB);   // 8..16   dead after QKV
  short* v_bf = (short*)(ws + 16 * MB);  // 16..24  dead after QKV
  short* ctx  = (short*)(ws + 24 * MB);  // 24..32  attn out, dead after Wo
  short* Qp   = (short*)(ws + 32 * MB);  // 32..40  dead after attn
  short* Kp   = (short*)(ws + 40 * MB);  // 40..48  dead after attn
  short* Vp   = (short*)(ws + 48 * MB);  // 48..56  dead after attn
  short* Wqt  = (short*)(ws + 56 * MB);  // 56..58
  short* Wkt  = (short*)(ws + 58 * MB);  // 58..60
  short* Wvt  = (short*)(ws + 60 * MB);  // 60..62
  short* Wot  = (short*)(ws + 62 * MB);  // 62..64
  short* W1t  = (short*)(ws + 64 * MB);  // 64..72
  short* W2t  = (short*)(ws + 72 * MB);  // 72..80
  short* hbuf = (short*)(ws + 80 * MB);  // 80..112 FFN1 out
  // Wo partials: live Wo-gemm -> LN1 (q/k/v_bf, Qp/Kp dead by then)
  float* pWo0 = (float*)(ws + 0);        // 0..16
  float* pWo1 = (float*)(ws + 32 * MB);  // 32..48
  float* x_f32 = (float*)(ws + 16 * MB); // 16..32  LN1 out (v_bf/ctx dead)
  short* x_bf  = (short*)(ws + 48 * MB); // 48..56  LN1 out (Vp dead)
  // FFN2 partials: live FFN2 -> LN2 (pWo dead after LN1)
  float* pF0 = (float*)(ws + 0);         // 0..16
  float* pF1 = (float*)(ws + 32 * MB);   // 32..48

  // 1. activations -> bf16 + all weight transposes (ONE dispatch)
  prep_kernel<<<15360, 256, 0, stream>>>(query, keyi, values,
                                         q_bf, k_bf, v_bf,
                                         Wq, Wk, Wv, Wo, W1, W2,
                                         Wqt, Wkt, Wvt, Wot, W1t, W2t);
  // 2. fused QKV projections -> [B,H,S,64] bf16 (768 blocks, 2/CU)
  gsp_qkv<<<dim3(32, 8, 3), 256, 0, stream>>>(q_bf, k_bf, v_bf,
                                              Wqt, Wkt, Wvt,
                                              bq, bk, bv, Qp, Kp, Vp);
  // 3. flash attention (key-split, 512 blocks co-resident 2/CU) -> ctx
  attn_kernel<<<dim3(32, 16), 256, 0, stream>>>(Qp, Kp, Vp, maskp, ctx);
  // 4. output projection, split-K=2 (512 blocks, 2/CU) -> partials
  gsp_wo<<<dim3(32, 8, 2), 256, 0, stream>>>(ctx, Wot, bo, pWo0, pWo1);
  // 5. LN1(p0+p1+query) -> x (f32 + bf16)
  ln_comb_kernel<<<4096, 256, 0, stream>>>(pWo0, pWo1, query, ln1_g, ln1_b,
                                           x_f32, x_bf);
  // 6. FFN1 (+relu) -> h bf16 [4096,4096] (1024 blocks, 2/CU x2 rounds)
  gsp_ffn1<<<dim3(32, 32), 256, 0, stream>>>(x_bf, W1t, b1, hbuf);
  // 7. FFN2, split-K=2 (512 blocks, 2/CU) -> partials
  gsp_ffn2<<<dim3(32, 8, 2), 256, 0, stream>>>(hbuf, W2t, b2, pF0, pF1);
  // 8. LN2(p0+p1+x) -> out f32
  ln_comb_kernel<<<4096, 256, 0, stream>>>(pF0, pF1, x_f32, ln2_g, ln2_b,
                                           out, nullptr);

  (void)in_sizes; (void)n_in; (void)out_size; (void)ws_size;
}